// Round 1
// baseline (1468.852 us; speedup 1.0000x reference)
//
#include <hip/hip_runtime.h>
#include <math.h>

#define EPSF   1e-15f
#define CLIP1  0.99999988f   /* fp32(1 - 1e-7) */
#define MAXNRM 0.99999f      /* (1 - 1e-5)/sqrt(c), c = 1 */

// ---------------------------------------------------------------- utilities
__device__ __forceinline__ float wred(float x) {
#pragma unroll
  for (int o = 32; o; o >>= 1) x += __shfl_xor(x, o);
  return x;
}

// ---------------------------------------------------------------- z column norms^2
__global__ __launch_bounds__(256) void k_znorm(const float* __restrict__ Z1,
                                               const float* __restrict__ Z2,
                                               float* __restrict__ ZN2) {
  int mat = blockIdx.x / 9, chunk = blockIdx.x % 9;
  const float* Z = mat ? Z2 : Z1;
  int t = threadIdx.x;
  float acc = 0.f;
  for (int k = chunk * 256; k < chunk * 256 + 256; ++k) {
    float z = Z[k * 256 + t];
    acc = fmaf(z, z, acc);
  }
  atomicAdd(&ZN2[mat * 256 + t], acc);
}

// ---------------------------------------------------------------- x[B,C,H,W] -> xl,v,nv2
__global__ __launch_bounds__(256) void k_pre1(const float* __restrict__ X,
                                              float* __restrict__ XL,
                                              float* __restrict__ V,
                                              float* __restrict__ NV2,
                                              float scale) {
  __shared__ float tile[256 * 33];
  __shared__ float facs[32];
  const int b = blockIdx.x >> 5, h = blockIdx.x & 31;
  const int t = threadIdx.x;
  for (int c0 = 0; c0 < 256; c0 += 8) {
    int c = c0 + (t >> 5), w = t & 31;
    tile[c * 33 + w] = X[((b * 256 + c) * 32 + h) * 32 + w];
  }
  __syncthreads();
  {
    int w = t >> 3, s = t & 7;
    float n2 = 0.f;
#pragma unroll 8
    for (int i = 0; i < 32; ++i) {
      float xv = tile[(s + 8 * i) * 33 + w];
      n2 = fmaf(xv, xv, n2);
    }
    n2 += __shfl_xor(n2, 1); n2 += __shfl_xor(n2, 2); n2 += __shfl_xor(n2, 4);
    float n = sqrtf(fmaxf(n2, EPSF));
    float fac = atanhf(fminf(n, CLIP1)) / n * scale;
    if (s == 0) {
      facs[w] = fac;
      NV2[blockIdx.x * 32 + w] = fac * fac * n2;
    }
  }
  __syncthreads();
  const int g = t & 63;
  const int pix0 = blockIdx.x * 32;
#pragma unroll
  for (int it = 0; it < 8; ++it) {
    int p = (t >> 6) + it * 4;
    float f = facs[p];
    float4 val;
    val.x = tile[(g * 4 + 0) * 33 + p];
    val.y = tile[(g * 4 + 1) * 33 + p];
    val.z = tile[(g * 4 + 2) * 33 + p];
    val.w = tile[(g * 4 + 3) * 33 + p];
    *(float4*)(XL + (size_t)(pix0 + p) * 256 + g * 4) = val;
    float4 vv = make_float4(val.x * f, val.y * f, val.z * f, val.w * f);
    *(float4*)(V + (size_t)(pix0 + p) * 256 + g * 4) = vv;
  }
}

// ---------------------------------------------------------------- h[N,C] -> v,nv2
__global__ __launch_bounds__(256) void k_preB(const float* __restrict__ Hin,
                                              float* __restrict__ V,
                                              float* __restrict__ NV2,
                                              float scale) {
  int pix = blockIdx.x * 4 + (threadIdx.x >> 6);
  int lane = threadIdx.x & 63;
  float4 hv = ((const float4*)Hin)[pix * 64 + lane];
  float n2 = wred(hv.x * hv.x + hv.y * hv.y + hv.z * hv.z + hv.w * hv.w);
  float n = sqrtf(fmaxf(n2, EPSF));
  float fac = atanhf(fminf(n, CLIP1)) / n * scale;
  ((float4*)V)[pix * 64 + lane] =
      make_float4(hv.x * fac, hv.y * fac, hv.z * fac, hv.w * fac);
  if (lane == 0) NV2[pix] = fac * fac * n2;
}

// ---------------------------------------------------------------- 3x3 box sum of nv2
__global__ __launch_bounds__(256) void k_boxsum(const float* __restrict__ NV2,
                                                float* __restrict__ P2) {
  int pix = blockIdx.x * 256 + threadIdx.x;
  int hw = pix & 1023, hh = hw >> 5, ww = hw & 31, base = pix & ~1023;
  float s = 0.f;
#pragma unroll
  for (int di = -1; di <= 1; ++di)
#pragma unroll
    for (int dj = -1; dj <= 1; ++dj) {
      int sh = hh + di, sw = ww + dj;
      if ((unsigned)sh < 32u && (unsigned)sw < 32u) s += NV2[base + sh * 32 + sw];
    }
  P2[pix] = s;
}

// ---------------------------------------------------------------- implicit-GEMM conv
// S[m, j] = sum_{tap, cin} V[neighbor(m,tap), cin] * Z[tap*256+cin, j]
// tile 128 rows x 64 cols, BK = 32, 8x4 microtile, 256 threads
__global__ __launch_bounds__(256) void k_gemm(const float* __restrict__ V,
                                              const float* __restrict__ Z,
                                              float* __restrict__ S) {
  __shared__ float As[32 * 132];  // [kk][r], pad 132 (16B aligned rows)
  __shared__ float Bs[32 * 68];   // [kk][cc]
  const int tx = threadIdx.x & 15, ty = threadIdx.x >> 4;
  const int col0 = blockIdx.x * 64, row0 = blockIdx.y * 128;
  const int kk = threadIdx.x & 31, rbase = threadIdx.x >> 5;
  const int cc = threadIdx.x & 63, kr = threadIdx.x >> 6;
  float acc[8][4] = {};
  for (int kt = 0; kt < 72; ++kt) {
    const int k0 = kt * 32;
    const int tap = k0 >> 8, cin0 = k0 & 255;
    const int di = tap / 3 - 1, dj = tap % 3 - 1;
    __syncthreads();
#pragma unroll
    for (int it = 0; it < 16; ++it) {
      int r = rbase + it * 8;
      int m = row0 + r;
      int hh = (m >> 5) & 31, ww = m & 31;
      int sh = hh + di, sw = ww + dj;
      float val = 0.f;
      if ((unsigned)sh < 32u && (unsigned)sw < 32u)
        val = V[((m & ~1023) + sh * 32 + sw) * 256 + cin0 + kk];
      As[kk * 132 + r] = val;
    }
#pragma unroll
    for (int it = 0; it < 8; ++it) {
      int krow = kr + it * 4;
      Bs[krow * 68 + cc] = Z[(k0 + krow) * 256 + col0 + cc];
    }
    __syncthreads();
#pragma unroll
    for (int k = 0; k < 32; ++k) {
      float4 a0 = *(const float4*)(As + k * 132 + ty * 8);
      float4 a1 = *(const float4*)(As + k * 132 + ty * 8 + 4);
      float4 bv = *(const float4*)(Bs + k * 68 + tx * 4);
      float a[8] = {a0.x, a0.y, a0.z, a0.w, a1.x, a1.y, a1.z, a1.w};
      float b[4] = {bv.x, bv.y, bv.z, bv.w};
#pragma unroll
      for (int i = 0; i < 8; ++i)
#pragma unroll
        for (int j = 0; j < 4; ++j) acc[i][j] = fmaf(a[i], b[j], acc[i][j]);
    }
  }
#pragma unroll
  for (int i = 0; i < 8; ++i) {
    float4 o = make_float4(acc[i][0], acc[i][1], acc[i][2], acc[i][3]);
    *(float4*)(S + (size_t)(row0 + ty * 8 + i) * 256 + col0 + tx * 4) = o;
  }
}

// ---------------------------------------------------------------- Poincare-FC epilogue
__global__ __launch_bounds__(256) void k_fcepi(const float* __restrict__ S,
                                               const float* __restrict__ P2,
                                               const float* __restrict__ ZN2,
                                               float* __restrict__ Hout) {
  int pix = blockIdx.x * 4 + (threadIdx.x >> 6);
  int lane = threadIdx.x & 63;
  float4 sv = ((const float4*)S)[pix * 64 + lane];
  float4 z2 = ((const float4*)ZN2)[lane];
  float p2 = P2[pix];
  float np = sqrtf(fmaxf(p2, EPSF));
  float un = tanhf(np);
  float f = un / np;
  if (un > MAXNRM) f *= MAXNRM / un;
  float u2 = f * f * p2;
  float lam = 2.f / fmaxf(1.f - u2, EPSF);
  float lf = lam * f;
  float zn[4] = {sqrtf(fmaxf(z2.x, EPSF)), sqrtf(fmaxf(z2.y, EPSF)),
                 sqrtf(fmaxf(z2.z, EPSF)), sqrtf(fmaxf(z2.w, EPSF))};
  float sval[4] = {sv.x, sv.y, sv.z, sv.w};
  float y[4];
#pragma unroll
  for (int k = 0; k < 4; ++k) {
    float d = 2.f * zn[k] * asinhf(lf * sval[k] / zn[k]);
    y[k] = sinhf(d);
  }
  float y2 = wred(y[0] * y[0] + y[1] * y[1] + y[2] * y[2] + y[3] * y[3]);
  float inv = 1.f / (1.f + sqrtf(1.f + y2));
  ((float4*)Hout)[pix * 64 + lane] =
      make_float4(y[0] * inv, y[1] * inv, y[2] * inv, y[3] * inv);
}

// ---------------------------------------------------------------- BN reduction 1
__global__ __launch_bounds__(256) void k_bnred1(const float* __restrict__ Hin,
                                                float* __restrict__ NUM,
                                                float* __restrict__ DEN) {
  __shared__ float snum[256];
  __shared__ float sden;
  int t = threadIdx.x;
  snum[t] = 0.f;
  if (t == 0) sden = 0.f;
  __syncthreads();
  int lane = t & 63, wv = t >> 6;
  float4 acc = make_float4(0.f, 0.f, 0.f, 0.f);
  float accd = 0.f;
  for (int it = 0; it < 32; ++it) {
    int pix = blockIdx.x * 128 + it * 4 + wv;
    float4 hv = ((const float4*)Hin)[pix * 64 + lane];
    float n2 = wred(hv.x * hv.x + hv.y * hv.y + hv.z * hv.z + hv.w * hv.w);
    float lam = 2.f / fmaxf(1.f - n2, EPSF);
    acc.x = fmaf(lam, hv.x, acc.x);
    acc.y = fmaf(lam, hv.y, acc.y);
    acc.z = fmaf(lam, hv.z, acc.z);
    acc.w = fmaf(lam, hv.w, acc.w);
    if (lane == 0) accd += lam - 1.f;
  }
  atomicAdd(&snum[lane * 4 + 0], acc.x);
  atomicAdd(&snum[lane * 4 + 1], acc.y);
  atomicAdd(&snum[lane * 4 + 2], acc.z);
  atomicAdd(&snum[lane * 4 + 3], acc.w);
  if (lane == 0) atomicAdd(&sden, accd);
  __syncthreads();
  atomicAdd(&NUM[t], snum[t]);
  if (t == 0) atomicAdd(DEN, sden);
}

// ---------------------------------------------------------------- BN midpoint + scalars
__global__ __launch_bounds__(256) void k_bnmid(const float* __restrict__ NUM,
                                               const float* __restrict__ DEN,
                                               const float* __restrict__ BIAS,
                                               float* __restrict__ MU,
                                               float* __restrict__ SCAL) {
  __shared__ float sb[4];
  int t = threadIdx.x, lane = t & 63, wv = t >> 6;
  auto bred = [&](float v) {
    v = wred(v);
    __syncthreads();
    if (lane == 0) sb[wv] = v;
    __syncthreads();
    return sb[0] + sb[1] + sb[2] + sb[3];
  };
  float m = NUM[t] / fmaxf(DEN[0], EPSF);
  float n2m = bred(m * m);
  float n = sqrtf(fmaxf(n2m, EPSF));
  float midf = tanhf(0.5f * atanhf(fminf(n, CLIP1))) / n;
  float mu = m * midf;
  MU[t] = mu;
  float bv = BIAS[t];
  float bias2 = bred(bv * bv);
  float mubias = bred(bv * mu);
  if (t == 0) {
    float mu2 = midf * midf * n2m;
    SCAL[0] = mu2;
    SCAL[1] = 2.f / fmaxf(1.f - mu2, EPSF);
    SCAL[2] = bias2;
    SCAL[3] = 2.f / fmaxf(1.f - bias2, EPSF);
    SCAL[4] = mubias;
  }
}

// ---------------------------------------------------------------- BN reduction 2 (var)
__global__ __launch_bounds__(256) void k_bnred2(const float* __restrict__ Hin,
                                                const float* __restrict__ MU,
                                                const float* __restrict__ SCAL,
                                                float* __restrict__ VAR) {
  __shared__ float sp[4];
  int t = threadIdx.x, lane = t & 63, wv = t >> 6;
  int pix = blockIdx.x * 4 + wv;
  float4 hv = ((const float4*)Hin)[pix * 64 + lane];
  float4 muv = ((const float4*)MU)[lane];
  float mu2 = SCAL[0];
  float x2 = wred(hv.x * hv.x + hv.y * hv.y + hv.z * hv.z + hv.w * hv.w);
  float xmu = wred(hv.x * muv.x + hv.y * muv.y + hv.z * muv.z + hv.w * muv.w);
  float A = 1.f - 2.f * xmu + mu2;
  float B = 1.f - x2;
  float num2 = A * A * x2 + B * B * mu2 - 2.f * A * B * xmu;
  float den = fmaxf(1.f - 2.f * xmu + x2 * mu2, EPSF);
  float nn = sqrtf(fmaxf(num2 / (den * den), EPSF));
  float dist = 2.f * atanhf(fminf(nn, CLIP1));
  float d2 = dist * dist;
  if (lane == 0) sp[wv] = d2;
  __syncthreads();
  if (t == 0) atomicAdd(VAR, sp[0] + sp[1] + sp[2] + sp[3]);
}

// ---------------------------------------------------------------- BN transform (+relu / +residual)
template <int PATH>
__global__ __launch_bounds__(256) void k_bntrans(const float* __restrict__ Hin,
                                                 const float* __restrict__ MU,
                                                 const float* __restrict__ SCAL,
                                                 const float* __restrict__ BIAS,
                                                 const float* __restrict__ WEIGHT,
                                                 const float* __restrict__ VAR,
                                                 const float* __restrict__ RES,
                                                 float* __restrict__ OUT) {
  int pix = blockIdx.x * 4 + (threadIdx.x >> 6);
  int lane = threadIdx.x & 63;
  float4 xv4 = ((const float4*)Hin)[pix * 64 + lane];
  float4 mu4 = ((const float4*)MU)[lane];
  float4 bb4 = ((const float4*)BIAS)[lane];
  float mu2 = SCAL[0], lam_mu = SCAL[1], bias2 = SCAL[2], lam_bias = SCAL[3],
        mubias = SCAL[4];
  float var = VAR[0] * (1.f / 16384.f);
  float rstd = sqrtf(WEIGHT[0] / fmaxf(var, EPSF));
  float x[4] = {xv4.x, xv4.y, xv4.z, xv4.w};
  float mm[4] = {mu4.x, mu4.y, mu4.z, mu4.w};
  float bs[4] = {bb4.x, bb4.y, bb4.z, bb4.w};
  float x2 = wred(x[0] * x[0] + x[1] * x[1] + x[2] * x[2] + x[3] * x[3]);
  float xmu = wred(x[0] * mm[0] + x[1] * mm[1] + x[2] * mm[2] + x[3] * mm[3]);
  // d = mobius_add(-mu, x)
  float P = 1.f - 2.f * xmu + x2, Q = 1.f - mu2;
  float den1i = 1.f / fmaxf(1.f - 2.f * xmu + mu2 * x2, EPSF);
  float d[4];
#pragma unroll
  for (int k = 0; k < 4; ++k) d[k] = (Q * x[k] - P * mm[k]) * den1i;
  float nd2 = wred(d[0] * d[0] + d[1] * d[1] + d[2] * d[2] + d[3] * d[3]);
  float nd = sqrtf(fmaxf(nd2, EPSF));
  float vfac = (2.f / lam_mu) * atanhf(fminf(nd, CLIP1)) / nd;
  float v[4];
#pragma unroll
  for (int k = 0; k < 4; ++k) v[k] = vfac * d[k];
  // gyration(bias, -mu, v) * lam_mu/lam_bias * rstd
  float uw = wred(bs[0] * v[0] + bs[1] * v[1] + bs[2] * v[2] + bs[3] * v[3]);
  float mv = wred(mm[0] * v[0] + mm[1] * v[1] + mm[2] * v[2] + mm[3] * v[3]);
  float vw = -mv, uv = -mubias;
  float ga = -(uw * mu2) - vw + 2.f * uv * vw;
  float gb = -(vw * bias2) + uw;
  float ddi = 1.f / fmaxf(1.f + 2.f * uv + bias2 * mu2, EPSF);
  float sgy = (lam_mu / lam_bias) * rstd;
  float u[4];
#pragma unroll
  for (int k = 0; k < 4; ++k)
    u[k] = (v[k] + 2.f * (ga * bs[k] - gb * mm[k]) * ddi) * sgy;
  // expmap(bias, u)
  float nu2 = wred(u[0] * u[0] + u[1] * u[1] + u[2] * u[2] + u[3] * u[3]);
  float bu = wred(bs[0] * u[0] + bs[1] * u[1] + bs[2] * u[2] + bs[3] * u[3]);
  float nu = sqrtf(fmaxf(nu2, EPSF));
  float sfac = tanhf(lam_bias * nu * 0.5f) / nu;
  float y2 = sfac * sfac * nu2, xy = sfac * bu;
  float P2 = 1.f + 2.f * xy + y2, Q2 = 1.f - bias2;
  float den2i = 1.f / fmaxf(1.f + 2.f * xy + bias2 * y2, EPSF);
  float r[4];
#pragma unroll
  for (int k = 0; k < 4; ++k) r[k] = (P2 * bs[k] + Q2 * sfac * u[k]) * den2i;
  float nr2 = wred(r[0] * r[0] + r[1] * r[1] + r[2] * r[2] + r[3] * r[3]);
  float nr = sqrtf(fmaxf(nr2, EPSF));
  if (nr > MAXNRM) {
    float sc = MAXNRM / nr;
#pragma unroll
    for (int k = 0; k < 4; ++k) r[k] *= sc;
    nr = MAXNRM;
  }
  if (PATH == 2) {
    float h2 = nr * nr;
    float4 rs4 = ((const float4*)RES)[pix * 64 + lane];
    float rr[4] = {rs4.x, rs4.y, rs4.z, rs4.w};
    float y2r = wred(rr[0] * rr[0] + rr[1] * rr[1] + rr[2] * rr[2] + rr[3] * rr[3]);
    float xyr = wred(r[0] * rr[0] + r[1] * rr[1] + r[2] * rr[2] + r[3] * rr[3]);
    float Pm = 1.f + 2.f * xyr + y2r, Qm = 1.f - h2;
    float denmi = 1.f / fmaxf(1.f + 2.f * xyr + h2 * y2r, EPSF);
#pragma unroll
    for (int k = 0; k < 4; ++k) r[k] = (Pm * r[k] + Qm * rr[k]) * denmi;
    nr2 = wred(r[0] * r[0] + r[1] * r[1] + r[2] * r[2] + r[3] * r[3]);
    nr = sqrtf(fmaxf(nr2, EPSF));
  }
  // hrelu
  float tf = atanhf(fminf(nr, CLIP1)) / nr;
  float tr[4];
#pragma unroll
  for (int k = 0; k < 4; ++k) tr[k] = fmaxf(tf * r[k], 0.f);
  float nt2 = wred(tr[0] * tr[0] + tr[1] * tr[1] + tr[2] * tr[2] + tr[3] * tr[3]);
  float nt = sqrtf(fmaxf(nt2, EPSF));
  float une = tanhf(nt);
  float ef = une / nt;
  if (une > MAXNRM) ef *= MAXNRM / une;
  ((float4*)OUT)[pix * 64 + lane] =
      make_float4(ef * tr[0], ef * tr[1], ef * tr[2], ef * tr[3]);
}

// ---------------------------------------------------------------- [N,C] -> [B,C,H,W]
__global__ __launch_bounds__(256) void k_outT(const float* __restrict__ Src,
                                              float* __restrict__ Out) {
  __shared__ float tile[256 * 33];
  int b = blockIdx.x >> 5, h = blockIdx.x & 31;
  int t = threadIdx.x;
  int pix0 = blockIdx.x * 32;
  int g = t & 63;
#pragma unroll
  for (int it = 0; it < 8; ++it) {
    int p = (t >> 6) + it * 4;
    float4 v = ((const float4*)Src)[(size_t)(pix0 + p) * 64 + g];
    tile[(g * 4 + 0) * 33 + p] = v.x;
    tile[(g * 4 + 1) * 33 + p] = v.y;
    tile[(g * 4 + 2) * 33 + p] = v.z;
    tile[(g * 4 + 3) * 33 + p] = v.w;
  }
  __syncthreads();
  for (int c0 = 0; c0 < 256; c0 += 8) {
    int c = c0 + (t >> 5), w = t & 31;
    Out[((b * 256 + c) * 32 + h) * 32 + w] = tile[c * 33 + w];
  }
}

// ---------------------------------------------------------------- launch
extern "C" void kernel_launch(void* const* d_in, const int* in_sizes, int n_in,
                              void* d_out, int out_size, void* d_ws, size_t ws_size,
                              hipStream_t stream) {
  (void)in_sizes; (void)n_in; (void)out_size; (void)ws_size;
  const float* x  = (const float*)d_in[0];
  const float* z1 = (const float*)d_in[1];
  const float* z2 = (const float*)d_in[2];
  const float* w1 = (const float*)d_in[3];
  const float* b1 = (const float*)d_in[4];
  const float* w2 = (const float*)d_in[5];
  const float* b2 = (const float*)d_in[6];
  float* out = (float*)d_out;
  float* ws = (float*)d_ws;

  float* zn2  = ws;          // 512
  float* num  = ws + 512;    // 256
  float* den  = ws + 768;    // 1
  float* var  = ws + 769;    // 1
  float* mu   = ws + 772;    // 256 (16B aligned)
  float* scal = ws + 1028;   // 8
  float* nv2  = ws + 2048;   // 16384
  float* p2   = ws + 2048 + 16384;
  float* xl   = ws + 2048 + 32768;           // 16 MB
  float* v    = xl + 4194304;                // 16 MB
  float* s    = v + 4194304;                 // 16 MB
  float* h    = s + 4194304;                 // 16 MB

  // beta(n/2,1/2)/beta(Cin/2,1/2), n = 2304, Cin = 256 (lgamma(0.5) cancels)
  double lb = (lgamma(1152.0) - lgamma(1152.5)) - (lgamma(128.0) - lgamma(128.5));
  float scale = (float)exp(lb);

  hipMemsetAsync(ws, 0, 2048 * sizeof(float), stream);
  k_znorm<<<18, 256, 0, stream>>>(z1, z2, zn2);

  // ---- conv1
  k_pre1<<<512, 256, 0, stream>>>(x, xl, v, nv2, scale);
  k_boxsum<<<64, 256, 0, stream>>>(nv2, p2);
  k_gemm<<<dim3(4, 128), 256, 0, stream>>>(v, z1, s);
  k_fcepi<<<4096, 256, 0, stream>>>(s, p2, zn2, h);
  // ---- bn1 + relu (in place)
  k_bnred1<<<128, 256, 0, stream>>>(h, num, den);
  k_bnmid<<<1, 256, 0, stream>>>(num, den, b1, mu, scal);
  k_bnred2<<<4096, 256, 0, stream>>>(h, mu, scal, var);
  k_bntrans<1><<<4096, 256, 0, stream>>>(h, mu, scal, b1, w1, var, xl, h);

  // ---- conv2
  hipMemsetAsync(num, 0, 258 * sizeof(float), stream);  // num,den,var
  k_preB<<<4096, 256, 0, stream>>>(h, v, nv2, scale);
  k_boxsum<<<64, 256, 0, stream>>>(nv2, p2);
  k_gemm<<<dim3(4, 128), 256, 0, stream>>>(v, z2, s);
  k_fcepi<<<4096, 256, 0, stream>>>(s, p2, zn2 + 256, h);
  // ---- bn2 + residual + relu -> s (channel-last), then transpose
  k_bnred1<<<128, 256, 0, stream>>>(h, num, den);
  k_bnmid<<<1, 256, 0, stream>>>(num, den, b2, mu, scal);
  k_bnred2<<<4096, 256, 0, stream>>>(h, mu, scal, var);
  k_bntrans<2><<<4096, 256, 0, stream>>>(h, mu, scal, b2, w2, var, xl, s);
  k_outT<<<512, 256, 0, stream>>>(s, out);
}

// Round 2
// 537.784 us; speedup vs baseline: 2.7313x; 2.7313x over previous
//
#include <hip/hip_runtime.h>
#include <math.h>

#define EPSF   1e-15f
#define CLIP1  0.99999988f   /* fp32(1 - 1e-7) */
#define MAXNRM 0.99999f      /* (1 - 1e-5)/sqrt(c), c = 1 */

typedef __bf16 bf16x8 __attribute__((ext_vector_type(8)));
typedef float floatx4 __attribute__((ext_vector_type(4)));

// ---------------------------------------------------------------- utilities
__device__ __forceinline__ float wred(float x) {
#pragma unroll
  for (int o = 32; o; o >>= 1) x += __shfl_xor(x, o);
  return x;
}

__device__ __forceinline__ unsigned short f2bf(float f) {
  unsigned int u = __float_as_uint(f);
  u += 0x7fffu + ((u >> 16) & 1u);   // RNE
  return (unsigned short)(u >> 16);
}

__device__ __forceinline__ void gl_lds16(const ushort* g, ushort* l) {
  __builtin_amdgcn_global_load_lds(
      (const __attribute__((address_space(1))) void*)g,
      (__attribute__((address_space(3))) void*)l, 16, 0, 0);
}

// ---------------------------------------------------------------- z column norms^2
__global__ __launch_bounds__(256) void k_znorm(const float* __restrict__ Z1,
                                               const float* __restrict__ Z2,
                                               float* __restrict__ ZN2) {
  int mat = blockIdx.x / 9, chunk = blockIdx.x % 9;
  const float* Z = mat ? Z2 : Z1;
  int t = threadIdx.x;
  float acc = 0.f;
  for (int k = chunk * 256; k < chunk * 256 + 256; ++k) {
    float z = Z[k * 256 + t];
    acc = fmaf(z, z, acc);
  }
  atomicAdd(&ZN2[mat * 256 + t], acc);
}

// ---------------------------------------------------------------- Z -> fragment-ordered bf16
// ZF[mat][colblk(2)][k32(72)][ct(8)] block of 1KB: lane l, j: Z[k32*32+(l>>4)*8+j][colblk*128+ct*16+(l&15)]
__global__ __launch_bounds__(256) void k_zpack(const float* __restrict__ Z1,
                                               const float* __restrict__ Z2,
                                               ushort* __restrict__ ZF) {
  __shared__ float zs[32 * 256];
  int kt = blockIdx.x, mat = blockIdx.y;
  const float* Z = mat ? Z2 : Z1;
  ushort* out = ZF + (size_t)mat * 589824;
  int t = threadIdx.x;
  const float4* src = (const float4*)(Z + kt * 32 * 256);
  float4* dst4 = (float4*)zs;
#pragma unroll
  for (int i = 0; i < 8; ++i) dst4[t + i * 256] = src[t + i * 256];
  __syncthreads();
  int l = t & 63, sub = t >> 6;
  for (int i = 0; i < 4; ++i) {
    int combo = sub * 4 + i;
    int colblk = combo >> 3, ct = combo & 7;
    int col = colblk * 128 + ct * 16 + (l & 15);
    int krow = (l >> 4) * 8;
    unsigned int pk[4];
#pragma unroll
    for (int j = 0; j < 4; ++j) {
      unsigned int lo = f2bf(zs[(krow + 2 * j) * 256 + col]);
      unsigned int hi = f2bf(zs[(krow + 2 * j + 1) * 256 + col]);
      pk[j] = lo | (hi << 16);
    }
    uint4* o = (uint4*)(out + ((size_t)(colblk * 72 + kt) * 8 + ct) * 512 + l * 8);
    *o = make_uint4(pk[0], pk[1], pk[2], pk[3]);
  }
}

// ---------------------------------------------------------------- x[B,C,H,W] -> xl fp32, Vp bf16(padded), nv2
__global__ __launch_bounds__(256) void k_pre1(const float* __restrict__ X,
                                              float* __restrict__ XL,
                                              ushort* __restrict__ Vp,
                                              float* __restrict__ NV2,
                                              float scale) {
  __shared__ float tile[256 * 33];
  __shared__ float facs[32];
  const int b = blockIdx.x >> 5, h = blockIdx.x & 31;
  const int t = threadIdx.x;
  for (int c0 = 0; c0 < 256; c0 += 8) {
    int c = c0 + (t >> 5), w = t & 31;
    tile[c * 33 + w] = X[((b * 256 + c) * 32 + h) * 32 + w];
  }
  __syncthreads();
  {
    int w = t >> 3, s = t & 7;
    float n2 = 0.f;
#pragma unroll 8
    for (int i = 0; i < 32; ++i) {
      float xv = tile[(s + 8 * i) * 33 + w];
      n2 = fmaf(xv, xv, n2);
    }
    n2 += __shfl_xor(n2, 1); n2 += __shfl_xor(n2, 2); n2 += __shfl_xor(n2, 4);
    float n = sqrtf(fmaxf(n2, EPSF));
    float fac = atanhf(fminf(n, CLIP1)) / n * scale;
    if (s == 0) {
      facs[w] = fac;
      NV2[blockIdx.x * 32 + w] = fac * fac * n2;
    }
  }
  __syncthreads();
  const int g = t & 63;
  const int pix0 = blockIdx.x * 32;
#pragma unroll
  for (int it = 0; it < 8; ++it) {
    int p = (t >> 6) + it * 4;
    float f = facs[p];
    float4 val;
    val.x = tile[(g * 4 + 0) * 33 + p];
    val.y = tile[(g * 4 + 1) * 33 + p];
    val.z = tile[(g * 4 + 2) * 33 + p];
    val.w = tile[(g * 4 + 3) * 33 + p];
    *(float4*)(XL + (size_t)(pix0 + p) * 256 + g * 4) = val;
    ushort4 vb;
    vb.x = f2bf(val.x * f); vb.y = f2bf(val.y * f);
    vb.z = f2bf(val.z * f); vb.w = f2bf(val.w * f);
    *(ushort4*)(Vp + ((size_t)((b * 34 + h + 1) * 34 + (p + 1))) * 256 + g * 4) = vb;
  }
}

// ---------------------------------------------------------------- h[N,C] -> Vp bf16(padded), nv2
__global__ __launch_bounds__(256) void k_preB(const float* __restrict__ Hin,
                                              ushort* __restrict__ Vp,
                                              float* __restrict__ NV2,
                                              float scale) {
  int pix = blockIdx.x * 4 + (threadIdx.x >> 6);
  int lane = threadIdx.x & 63;
  float4 hv = ((const float4*)Hin)[pix * 64 + lane];
  float n2 = wred(hv.x * hv.x + hv.y * hv.y + hv.z * hv.z + hv.w * hv.w);
  float n = sqrtf(fmaxf(n2, EPSF));
  float fac = atanhf(fminf(n, CLIP1)) / n * scale;
  int b = pix >> 10, hh = (pix >> 5) & 31, ww = pix & 31;
  ushort4 vb;
  vb.x = f2bf(hv.x * fac); vb.y = f2bf(hv.y * fac);
  vb.z = f2bf(hv.z * fac); vb.w = f2bf(hv.w * fac);
  *(ushort4*)(Vp + ((size_t)((b * 34 + hh + 1) * 34 + (ww + 1))) * 256 + lane * 4) = vb;
  if (lane == 0) NV2[pix] = fac * fac * n2;
}

// ---------------------------------------------------------------- 3x3 box sum of nv2
__global__ __launch_bounds__(256) void k_boxsum(const float* __restrict__ NV2,
                                                float* __restrict__ P2) {
  int pix = blockIdx.x * 256 + threadIdx.x;
  int hw = pix & 1023, hh = hw >> 5, ww = hw & 31, base = pix & ~1023;
  float s = 0.f;
#pragma unroll
  for (int di = -1; di <= 1; ++di)
#pragma unroll
    for (int dj = -1; dj <= 1; ++dj) {
      int sh = hh + di, sw = ww + dj;
      if ((unsigned)sh < 32u && (unsigned)sw < 32u) s += NV2[base + sh * 32 + sw];
    }
  P2[pix] = s;
}

// ---------------------------------------------------------------- MFMA implicit-GEMM conv
// S[16384,256] = im2col(Vp)[16384,2304] @ Z[2304,256], bf16 in, fp32 out
// tile 128x128, BK=64, 4 waves (64x64 quadrant), LDS double-buffered
__global__ __launch_bounds__(256) void k_gemm_mfma(const ushort* __restrict__ Vp,
                                                   const ushort* __restrict__ ZF,
                                                   float* __restrict__ S) {
  __shared__ ushort lds[32768];  // 2 bufs x (16KB A + 16KB B)
  const int t = threadIdx.x;
  const int w = t >> 6, l = t & 63;
  const int l15 = l & 15, l16 = l >> 4;
  const int col0 = blockIdx.x * 128, row0 = blockIdx.y * 128;
  const int rhalf = w & 1, chalf = w >> 1;
  const size_t cb72 = (size_t)blockIdx.x * 72;

  // A-gather bases for frag rows rt = w and w+4 (element offsets into padded Vp)
  int abase[2];
#pragma unroll
  for (int i = 0; i < 2; ++i) {
    int r = row0 + (w + i * 4) * 16 + l15;
    int b = r >> 10, h = (r >> 5) & 31, wc = r & 31;
    abase[i] = ((b * 34 + h + 1) * 34 + (wc + 1)) * 256 + l16 * 8;
  }

  floatx4 acc[4][4];
#pragma unroll
  for (int i = 0; i < 4; ++i)
#pragma unroll
    for (int j = 0; j < 4; ++j) acc[i][j] = (floatx4){0.f, 0.f, 0.f, 0.f};

  auto stage = [&](int buf, int kt) {
    int tap = kt >> 2, cin0 = (kt & 3) << 6;
    int koff = ((tap / 3 - 1) * 34 + (tap % 3 - 1)) * 256 + cin0;
    ushort* Ad = lds + buf * 16384;
    ushort* Bd = Ad + 8192;
#pragma unroll
    for (int ii = 0; ii < 4; ++ii) {
      int bi = w + ii * 4;          // s = bi>>3, rt = bi&7
      int s = bi >> 3;
      gl_lds16(Vp + abase[ii & 1] + koff + s * 32, Ad + bi * 512);
    }
#pragma unroll
    for (int ii = 0; ii < 4; ++ii) {
      int bi = w + ii * 4;
      int s = bi >> 3, ct = bi & 7;
      gl_lds16(ZF + ((cb72 + kt * 2 + s) * 8 + ct) * 512 + l * 8, Bd + bi * 512);
    }
  };

  auto compute = [&](int buf) {
    const ushort* Ab = lds + buf * 16384;
    const ushort* Bb = Ab + 8192;
    bf16x8 a[2][4], b[2][4];
#pragma unroll
    for (int s = 0; s < 2; ++s)
#pragma unroll
      for (int i = 0; i < 4; ++i) {
        a[s][i] = *(const bf16x8*)(Ab + (s * 8 + rhalf * 4 + i) * 512 + l * 8);
        b[s][i] = *(const bf16x8*)(Bb + (s * 8 + chalf * 4 + i) * 512 + l * 8);
      }
#pragma unroll
    for (int s = 0; s < 2; ++s)
#pragma unroll
      for (int i = 0; i < 4; ++i)
#pragma unroll
        for (int j = 0; j < 4; ++j)
          acc[i][j] = __builtin_amdgcn_mfma_f32_16x16x32_bf16(a[s][i], b[s][j],
                                                              acc[i][j], 0, 0, 0);
  };

  stage(0, 0);
  for (int kt = 0; kt < 36; ++kt) {
    __syncthreads();                       // drains stage(kt) (vmcnt) + joins compute(kt-1)
    if (kt + 1 < 36) stage((kt + 1) & 1, kt + 1);
    compute(kt & 1);
  }

#pragma unroll
  for (int i = 0; i < 4; ++i) {
    int r = row0 + rhalf * 64 + i * 16 + l16 * 4;
#pragma unroll
    for (int j = 0; j < 4; ++j) {
      int c = col0 + chalf * 64 + j * 16 + l15;
#pragma unroll
      for (int reg = 0; reg < 4; ++reg)
        S[(size_t)(r + reg) * 256 + c] = acc[i][j][reg];
    }
  }
}

// ---------------------------------------------------------------- Poincare-FC epilogue
__global__ __launch_bounds__(256) void k_fcepi(const float* __restrict__ S,
                                               const float* __restrict__ P2,
                                               const float* __restrict__ ZN2,
                                               float* __restrict__ Hout) {
  int pix = blockIdx.x * 4 + (threadIdx.x >> 6);
  int lane = threadIdx.x & 63;
  float4 sv = ((const float4*)S)[pix * 64 + lane];
  float4 z2 = ((const float4*)ZN2)[lane];
  float p2 = P2[pix];
  float np = sqrtf(fmaxf(p2, EPSF));
  float un = tanhf(np);
  float f = un / np;
  if (un > MAXNRM) f *= MAXNRM / un;
  float u2 = f * f * p2;
  float lam = 2.f / fmaxf(1.f - u2, EPSF);
  float lf = lam * f;
  float zn[4] = {sqrtf(fmaxf(z2.x, EPSF)), sqrtf(fmaxf(z2.y, EPSF)),
                 sqrtf(fmaxf(z2.z, EPSF)), sqrtf(fmaxf(z2.w, EPSF))};
  float sval[4] = {sv.x, sv.y, sv.z, sv.w};
  float y[4];
#pragma unroll
  for (int k = 0; k < 4; ++k) {
    float d = 2.f * zn[k] * asinhf(lf * sval[k] / zn[k]);
    y[k] = sinhf(d);
  }
  float y2 = wred(y[0] * y[0] + y[1] * y[1] + y[2] * y[2] + y[3] * y[3]);
  float inv = 1.f / (1.f + sqrtf(1.f + y2));
  ((float4*)Hout)[pix * 64 + lane] =
      make_float4(y[0] * inv, y[1] * inv, y[2] * inv, y[3] * inv);
}

// ---------------------------------------------------------------- BN reduction 1
__global__ __launch_bounds__(256) void k_bnred1(const float* __restrict__ Hin,
                                                float* __restrict__ NUM,
                                                float* __restrict__ DEN) {
  __shared__ float snum[256];
  __shared__ float sden;
  int t = threadIdx.x;
  snum[t] = 0.f;
  if (t == 0) sden = 0.f;
  __syncthreads();
  int lane = t & 63, wv = t >> 6;
  float4 acc = make_float4(0.f, 0.f, 0.f, 0.f);
  float accd = 0.f;
  for (int it = 0; it < 32; ++it) {
    int pix = blockIdx.x * 128 + it * 4 + wv;
    float4 hv = ((const float4*)Hin)[pix * 64 + lane];
    float n2 = wred(hv.x * hv.x + hv.y * hv.y + hv.z * hv.z + hv.w * hv.w);
    float lam = 2.f / fmaxf(1.f - n2, EPSF);
    acc.x = fmaf(lam, hv.x, acc.x);
    acc.y = fmaf(lam, hv.y, acc.y);
    acc.z = fmaf(lam, hv.z, acc.z);
    acc.w = fmaf(lam, hv.w, acc.w);
    if (lane == 0) accd += lam - 1.f;
  }
  atomicAdd(&snum[lane * 4 + 0], acc.x);
  atomicAdd(&snum[lane * 4 + 1], acc.y);
  atomicAdd(&snum[lane * 4 + 2], acc.z);
  atomicAdd(&snum[lane * 4 + 3], acc.w);
  if (lane == 0) atomicAdd(&sden, accd);
  __syncthreads();
  atomicAdd(&NUM[t], snum[t]);
  if (t == 0) atomicAdd(DEN, sden);
}

// ---------------------------------------------------------------- BN midpoint + scalars
__global__ __launch_bounds__(256) void k_bnmid(const float* __restrict__ NUM,
                                               const float* __restrict__ DEN,
                                               const float* __restrict__ BIAS,
                                               float* __restrict__ MU,
                                               float* __restrict__ SCAL) {
  __shared__ float sb[4];
  int t = threadIdx.x, lane = t & 63, wv = t >> 6;
  auto bred = [&](float v) {
    v = wred(v);
    __syncthreads();
    if (lane == 0) sb[wv] = v;
    __syncthreads();
    return sb[0] + sb[1] + sb[2] + sb[3];
  };
  float m = NUM[t] / fmaxf(DEN[0], EPSF);
  float n2m = bred(m * m);
  float n = sqrtf(fmaxf(n2m, EPSF));
  float midf = tanhf(0.5f * atanhf(fminf(n, CLIP1))) / n;
  float mu = m * midf;
  MU[t] = mu;
  float bv = BIAS[t];
  float bias2 = bred(bv * bv);
  float mubias = bred(bv * mu);
  if (t == 0) {
    float mu2 = midf * midf * n2m;
    SCAL[0] = mu2;
    SCAL[1] = 2.f / fmaxf(1.f - mu2, EPSF);
    SCAL[2] = bias2;
    SCAL[3] = 2.f / fmaxf(1.f - bias2, EPSF);
    SCAL[4] = mubias;
  }
}

// ---------------------------------------------------------------- BN reduction 2 (var)
__global__ __launch_bounds__(256) void k_bnred2(const float* __restrict__ Hin,
                                                const float* __restrict__ MU,
                                                const float* __restrict__ SCAL,
                                                float* __restrict__ VAR) {
  __shared__ float sp[4];
  int t = threadIdx.x, lane = t & 63, wv = t >> 6;
  int pix = blockIdx.x * 4 + wv;
  float4 hv = ((const float4*)Hin)[pix * 64 + lane];
  float4 muv = ((const float4*)MU)[lane];
  float mu2 = SCAL[0];
  float x2 = wred(hv.x * hv.x + hv.y * hv.y + hv.z * hv.z + hv.w * hv.w);
  float xmu = wred(hv.x * muv.x + hv.y * muv.y + hv.z * muv.z + hv.w * muv.w);
  float A = 1.f - 2.f * xmu + mu2;
  float B = 1.f - x2;
  float num2 = A * A * x2 + B * B * mu2 - 2.f * A * B * xmu;
  float den = fmaxf(1.f - 2.f * xmu + x2 * mu2, EPSF);
  float nn = sqrtf(fmaxf(num2 / (den * den), EPSF));
  float dist = 2.f * atanhf(fminf(nn, CLIP1));
  float d2 = dist * dist;
  if (lane == 0) sp[wv] = d2;
  __syncthreads();
  if (t == 0) atomicAdd(VAR, sp[0] + sp[1] + sp[2] + sp[3]);
}

// ---------------------------------------------------------------- BN transform (+relu / +residual)
template <int PATH>
__global__ __launch_bounds__(256) void k_bntrans(const float* __restrict__ Hin,
                                                 const float* __restrict__ MU,
                                                 const float* __restrict__ SCAL,
                                                 const float* __restrict__ BIAS,
                                                 const float* __restrict__ WEIGHT,
                                                 const float* __restrict__ VAR,
                                                 const float* __restrict__ RES,
                                                 float* __restrict__ OUT) {
  int pix = blockIdx.x * 4 + (threadIdx.x >> 6);
  int lane = threadIdx.x & 63;
  float4 xv4 = ((const float4*)Hin)[pix * 64 + lane];
  float4 mu4 = ((const float4*)MU)[lane];
  float4 bb4 = ((const float4*)BIAS)[lane];
  float mu2 = SCAL[0], lam_mu = SCAL[1], bias2 = SCAL[2], lam_bias = SCAL[3],
        mubias = SCAL[4];
  float var = VAR[0] * (1.f / 16384.f);
  float rstd = sqrtf(WEIGHT[0] / fmaxf(var, EPSF));
  float x[4] = {xv4.x, xv4.y, xv4.z, xv4.w};
  float mm[4] = {mu4.x, mu4.y, mu4.z, mu4.w};
  float bs[4] = {bb4.x, bb4.y, bb4.z, bb4.w};
  float x2 = wred(x[0] * x[0] + x[1] * x[1] + x[2] * x[2] + x[3] * x[3]);
  float xmu = wred(x[0] * mm[0] + x[1] * mm[1] + x[2] * mm[2] + x[3] * mm[3]);
  float P = 1.f - 2.f * xmu + x2, Q = 1.f - mu2;
  float den1i = 1.f / fmaxf(1.f - 2.f * xmu + mu2 * x2, EPSF);
  float d[4];
#pragma unroll
  for (int k = 0; k < 4; ++k) d[k] = (Q * x[k] - P * mm[k]) * den1i;
  float nd2 = wred(d[0] * d[0] + d[1] * d[1] + d[2] * d[2] + d[3] * d[3]);
  float nd = sqrtf(fmaxf(nd2, EPSF));
  float vfac = (2.f / lam_mu) * atanhf(fminf(nd, CLIP1)) / nd;
  float v[4];
#pragma unroll
  for (int k = 0; k < 4; ++k) v[k] = vfac * d[k];
  float uw = wred(bs[0] * v[0] + bs[1] * v[1] + bs[2] * v[2] + bs[3] * v[3]);
  float mv = wred(mm[0] * v[0] + mm[1] * v[1] + mm[2] * v[2] + mm[3] * v[3]);
  float vw = -mv, uv = -mubias;
  float ga = -(uw * mu2) - vw + 2.f * uv * vw;
  float gb = -(vw * bias2) + uw;
  float ddi = 1.f / fmaxf(1.f + 2.f * uv + bias2 * mu2, EPSF);
  float sgy = (lam_mu / lam_bias) * rstd;
  float u[4];
#pragma unroll
  for (int k = 0; k < 4; ++k)
    u[k] = (v[k] + 2.f * (ga * bs[k] - gb * mm[k]) * ddi) * sgy;
  float nu2 = wred(u[0] * u[0] + u[1] * u[1] + u[2] * u[2] + u[3] * u[3]);
  float bu = wred(bs[0] * u[0] + bs[1] * u[1] + bs[2] * u[2] + bs[3] * u[3]);
  float nu = sqrtf(fmaxf(nu2, EPSF));
  float sfac = tanhf(lam_bias * nu * 0.5f) / nu;
  float y2 = sfac * sfac * nu2, xy = sfac * bu;
  float P2 = 1.f + 2.f * xy + y2, Q2 = 1.f - bias2;
  float den2i = 1.f / fmaxf(1.f + 2.f * xy + bias2 * y2, EPSF);
  float r[4];
#pragma unroll
  for (int k = 0; k < 4; ++k) r[k] = (P2 * bs[k] + Q2 * sfac * u[k]) * den2i;
  float nr2 = wred(r[0] * r[0] + r[1] * r[1] + r[2] * r[2] + r[3] * r[3]);
  float nr = sqrtf(fmaxf(nr2, EPSF));
  if (nr > MAXNRM) {
    float sc = MAXNRM / nr;
#pragma unroll
    for (int k = 0; k < 4; ++k) r[k] *= sc;
    nr = MAXNRM;
  }
  if (PATH == 2) {
    float h2 = nr * nr;
    float4 rs4 = ((const float4*)RES)[pix * 64 + lane];
    float rr[4] = {rs4.x, rs4.y, rs4.z, rs4.w};
    float y2r = wred(rr[0] * rr[0] + rr[1] * rr[1] + rr[2] * rr[2] + rr[3] * rr[3]);
    float xyr = wred(r[0] * rr[0] + r[1] * rr[1] + r[2] * rr[2] + r[3] * rr[3]);
    float Pm = 1.f + 2.f * xyr + y2r, Qm = 1.f - h2;
    float denmi = 1.f / fmaxf(1.f + 2.f * xyr + h2 * y2r, EPSF);
#pragma unroll
    for (int k = 0; k < 4; ++k) r[k] = (Pm * r[k] + Qm * rr[k]) * denmi;
    nr2 = wred(r[0] * r[0] + r[1] * r[1] + r[2] * r[2] + r[3] * r[3]);
    nr = sqrtf(fmaxf(nr2, EPSF));
  }
  float tf = atanhf(fminf(nr, CLIP1)) / nr;
  float tr[4];
#pragma unroll
  for (int k = 0; k < 4; ++k) tr[k] = fmaxf(tf * r[k], 0.f);
  float nt2 = wred(tr[0] * tr[0] + tr[1] * tr[1] + tr[2] * tr[2] + tr[3] * tr[3]);
  float nt = sqrtf(fmaxf(nt2, EPSF));
  float une = tanhf(nt);
  float ef = une / nt;
  if (une > MAXNRM) ef *= MAXNRM / une;
  ((float4*)OUT)[pix * 64 + lane] =
      make_float4(ef * tr[0], ef * tr[1], ef * tr[2], ef * tr[3]);
}

// ---------------------------------------------------------------- [N,C] -> [B,C,H,W]
__global__ __launch_bounds__(256) void k_outT(const float* __restrict__ Src,
                                              float* __restrict__ Out) {
  __shared__ float tile[256 * 33];
  int b = blockIdx.x >> 5, h = blockIdx.x & 31;
  int t = threadIdx.x;
  int pix0 = blockIdx.x * 32;
  int g = t & 63;
#pragma unroll
  for (int it = 0; it < 8; ++it) {
    int p = (t >> 6) + it * 4;
    float4 v = ((const float4*)Src)[(size_t)(pix0 + p) * 64 + g];
    tile[(g * 4 + 0) * 33 + p] = v.x;
    tile[(g * 4 + 1) * 33 + p] = v.y;
    tile[(g * 4 + 2) * 33 + p] = v.z;
    tile[(g * 4 + 3) * 33 + p] = v.w;
  }
  __syncthreads();
  for (int c0 = 0; c0 < 256; c0 += 8) {
    int c = c0 + (t >> 5), w = t & 31;
    Out[((b * 256 + c) * 32 + h) * 32 + w] = tile[c * 33 + w];
  }
}

// ---------------------------------------------------------------- launch
extern "C" void kernel_launch(void* const* d_in, const int* in_sizes, int n_in,
                              void* d_out, int out_size, void* d_ws, size_t ws_size,
                              hipStream_t stream) {
  (void)in_sizes; (void)n_in; (void)out_size; (void)ws_size;
  const float* x  = (const float*)d_in[0];
  const float* z1 = (const float*)d_in[1];
  const float* z2 = (const float*)d_in[2];
  const float* w1 = (const float*)d_in[3];
  const float* b1 = (const float*)d_in[4];
  const float* w2 = (const float*)d_in[5];
  const float* b2 = (const float*)d_in[6];
  float* out = (float*)d_out;
  float* ws = (float*)d_ws;

  float* zn2  = ws;          // 512
  float* num  = ws + 512;    // 256
  float* den  = ws + 768;    // 1
  float* var  = ws + 769;    // 1
  float* mu   = ws + 772;    // 256
  float* scal = ws + 1028;   // 8
  float* nv2  = ws + 2048;          // 16384
  float* p2   = ws + 2048 + 16384;  // 16384
  float* xl   = ws + 34816;         // 16 MB
  float* h    = xl + 4194304;       // 16 MB
  float* s    = h + 4194304;        // 16 MB
  ushort* Vp  = (ushort*)(s + 4194304);  // 16*34*34*256 bf16 = 9.47 MB
  ushort* ZF  = Vp + 4734976;            // 2 x 589824 bf16 = 2.36 MB

  double lb = (lgamma(1152.0) - lgamma(1152.5)) - (lgamma(128.0) - lgamma(128.5));
  float scale = (float)exp(lb);

  hipMemsetAsync(ws, 0, 2048 * sizeof(float), stream);
  hipMemsetAsync(Vp, 0, (size_t)4734976 * 2, stream);  // zero padding borders
  k_znorm<<<18, 256, 0, stream>>>(z1, z2, zn2);
  k_zpack<<<dim3(72, 2), 256, 0, stream>>>(z1, z2, ZF);

  // ---- conv1
  k_pre1<<<512, 256, 0, stream>>>(x, xl, Vp, nv2, scale);
  k_boxsum<<<64, 256, 0, stream>>>(nv2, p2);
  k_gemm_mfma<<<dim3(2, 128), 256, 0, stream>>>(Vp, ZF, s);
  k_fcepi<<<4096, 256, 0, stream>>>(s, p2, zn2, h);
  // ---- bn1 + relu (in place)
  k_bnred1<<<128, 256, 0, stream>>>(h, num, den);
  k_bnmid<<<1, 256, 0, stream>>>(num, den, b1, mu, scal);
  k_bnred2<<<4096, 256, 0, stream>>>(h, mu, scal, var);
  k_bntrans<1><<<4096, 256, 0, stream>>>(h, mu, scal, b1, w1, var, xl, h);

  // ---- conv2
  hipMemsetAsync(num, 0, 258 * sizeof(float), stream);  // num,den,var
  k_preB<<<4096, 256, 0, stream>>>(h, Vp, nv2, scale);
  k_boxsum<<<64, 256, 0, stream>>>(nv2, p2);
  k_gemm_mfma<<<dim3(2, 128), 256, 0, stream>>>(Vp, ZF + 589824, s);
  k_fcepi<<<4096, 256, 0, stream>>>(s, p2, zn2 + 256, h);
  // ---- bn2 + residual + relu -> s (channel-last), then transpose
  k_bnred1<<<128, 256, 0, stream>>>(h, num, den);
  k_bnmid<<<1, 256, 0, stream>>>(num, den, b2, mu, scal);
  k_bnred2<<<4096, 256, 0, stream>>>(h, mu, scal, var);
  k_bntrans<2><<<4096, 256, 0, stream>>>(h, mu, scal, b2, w2, var, xl, s);
  k_outT<<<512, 256, 0, stream>>>(s, out);
}

// Round 3
// 486.402 us; speedup vs baseline: 3.0198x; 1.1056x over previous
//
#include <hip/hip_runtime.h>
#include <math.h>

#define EPSF   1e-15f
#define CLIP1  0.99999988f   /* fp32(1 - 1e-7) */
#define MAXNRM 0.99999f      /* (1 - 1e-5)/sqrt(c), c = 1 */

typedef __bf16 bf16x8 __attribute__((ext_vector_type(8)));
typedef float floatx4 __attribute__((ext_vector_type(4)));

// ---------------------------------------------------------------- utilities
__device__ __forceinline__ float wred(float x) {
#pragma unroll
  for (int o = 32; o; o >>= 1) x += __shfl_xor(x, o);
  return x;
}

__device__ __forceinline__ unsigned short f2bf(float f) {
  unsigned int u = __float_as_uint(f);
  u += 0x7fffu + ((u >> 16) & 1u);   // RNE
  return (unsigned short)(u >> 16);
}

__device__ __forceinline__ void gl_lds16(const ushort* g, ushort* l) {
  __builtin_amdgcn_global_load_lds(
      (const __attribute__((address_space(1))) void*)g,
      (__attribute__((address_space(3))) void*)l, 16, 0, 0);
}

// ---------------------------------------------------------------- Z -> fragment-ordered bf16 (+ column norms^2)
// ZF block index (kt*16 + ctg), 1KB each: lane l, j: Z[kt*32+(l>>4)*8+j][ctg*16+(l&15)]
__global__ __launch_bounds__(256) void k_zpack(const float* __restrict__ Z1,
                                               const float* __restrict__ Z2,
                                               ushort* __restrict__ ZF,
                                               float* __restrict__ ZN2) {
  __shared__ float zs[32 * 256];
  int kt = blockIdx.x, mat = blockIdx.y;
  const float* Z = mat ? Z2 : Z1;
  ushort* out = ZF + (size_t)mat * 589824;
  int t = threadIdx.x;
  const float4* src = (const float4*)(Z + kt * 32 * 256);
  float4* dst4 = (float4*)zs;
#pragma unroll
  for (int i = 0; i < 8; ++i) dst4[t + i * 256] = src[t + i * 256];
  __syncthreads();
  // fused column-norm^2 partial (replaces k_znorm)
  {
    float acc = 0.f;
#pragma unroll 8
    for (int k = 0; k < 32; ++k) {
      float z = zs[k * 256 + t];
      acc = fmaf(z, z, acc);
    }
    atomicAdd(&ZN2[mat * 256 + t], acc);
  }
  int l = t & 63, sub = t >> 6;
  for (int i = 0; i < 4; ++i) {
    int combo = sub * 4 + i;                 // ctg 0..15
    int col = combo * 16 + (l & 15);
    int krow = (l >> 4) * 8;
    unsigned int pk[4];
#pragma unroll
    for (int j = 0; j < 4; ++j) {
      unsigned int lo = f2bf(zs[(krow + 2 * j) * 256 + col]);
      unsigned int hi = f2bf(zs[(krow + 2 * j + 1) * 256 + col]);
      pk[j] = lo | (hi << 16);
    }
    uint4* o = (uint4*)(out + ((size_t)(kt * 16 + combo)) * 512 + l * 8);
    *o = make_uint4(pk[0], pk[1], pk[2], pk[3]);
  }
}

// ---------------------------------------------------------------- x[B,C,H,W] -> xl fp32, Vp bf16(padded), nv2
__global__ __launch_bounds__(256) void k_pre1(const float* __restrict__ X,
                                              float* __restrict__ XL,
                                              ushort* __restrict__ Vp,
                                              float* __restrict__ NV2,
                                              float scale) {
  __shared__ float tile[256 * 33];
  __shared__ float facs[32];
  const int b = blockIdx.x >> 5, h = blockIdx.x & 31;
  const int t = threadIdx.x;
  for (int c0 = 0; c0 < 256; c0 += 8) {
    int c = c0 + (t >> 5), w = t & 31;
    tile[c * 33 + w] = X[((b * 256 + c) * 32 + h) * 32 + w];
  }
  __syncthreads();
  {
    int w = t >> 3, s = t & 7;
    float n2 = 0.f;
#pragma unroll 8
    for (int i = 0; i < 32; ++i) {
      float xv = tile[(s + 8 * i) * 33 + w];
      n2 = fmaf(xv, xv, n2);
    }
    n2 += __shfl_xor(n2, 1); n2 += __shfl_xor(n2, 2); n2 += __shfl_xor(n2, 4);
    float n = sqrtf(fmaxf(n2, EPSF));
    float fac = atanhf(fminf(n, CLIP1)) / n * scale;
    if (s == 0) {
      facs[w] = fac;
      NV2[blockIdx.x * 32 + w] = fac * fac * n2;
    }
  }
  __syncthreads();
  const int g = t & 63;
  const int pix0 = blockIdx.x * 32;
#pragma unroll
  for (int it = 0; it < 8; ++it) {
    int p = (t >> 6) + it * 4;
    float f = facs[p];
    float4 val;
    val.x = tile[(g * 4 + 0) * 33 + p];
    val.y = tile[(g * 4 + 1) * 33 + p];
    val.z = tile[(g * 4 + 2) * 33 + p];
    val.w = tile[(g * 4 + 3) * 33 + p];
    *(float4*)(XL + (size_t)(pix0 + p) * 256 + g * 4) = val;
    ushort4 vb;
    vb.x = f2bf(val.x * f); vb.y = f2bf(val.y * f);
    vb.z = f2bf(val.z * f); vb.w = f2bf(val.w * f);
    *(ushort4*)(Vp + ((size_t)((b * 34 + h + 1) * 34 + (p + 1))) * 256 + g * 4) = vb;
  }
}

// ---------------------------------------------------------------- h[N,C] -> Vp bf16(padded), nv2
__global__ __launch_bounds__(256) void k_preB(const float* __restrict__ Hin,
                                              ushort* __restrict__ Vp,
                                              float* __restrict__ NV2,
                                              float scale) {
  int pix = blockIdx.x * 4 + (threadIdx.x >> 6);
  int lane = threadIdx.x & 63;
  float4 hv = ((const float4*)Hin)[pix * 64 + lane];
  float n2 = wred(hv.x * hv.x + hv.y * hv.y + hv.z * hv.z + hv.w * hv.w);
  float n = sqrtf(fmaxf(n2, EPSF));
  float fac = atanhf(fminf(n, CLIP1)) / n * scale;
  int b = pix >> 10, hh = (pix >> 5) & 31, ww = pix & 31;
  ushort4 vb;
  vb.x = f2bf(hv.x * fac); vb.y = f2bf(hv.y * fac);
  vb.z = f2bf(hv.z * fac); vb.w = f2bf(hv.w * fac);
  *(ushort4*)(Vp + ((size_t)((b * 34 + hh + 1) * 34 + (ww + 1))) * 256 + lane * 4) = vb;
  if (lane == 0) NV2[pix] = fac * fac * n2;
}

// ---------------------------------------------------------------- 3x3 box sum of nv2
__global__ __launch_bounds__(256) void k_boxsum(const float* __restrict__ NV2,
                                                float* __restrict__ P2) {
  int pix = blockIdx.x * 256 + threadIdx.x;
  int hw = pix & 1023, hh = hw >> 5, ww = hw & 31, base = pix & ~1023;
  float s = 0.f;
#pragma unroll
  for (int di = -1; di <= 1; ++di)
#pragma unroll
    for (int dj = -1; dj <= 1; ++dj) {
      int sh = hh + di, sw = ww + dj;
      if ((unsigned)sh < 32u && (unsigned)sw < 32u) s += NV2[base + sh * 32 + sw];
    }
  P2[pix] = s;
}

// ---------------------------------------------------------------- MFMA implicit-GEMM conv
// S[16384,256] = im2col(Vp)[16384,2304] @ Z[2304,256], bf16 in, fp32 out
// tile 128 rows x 64 cols, BK=64, 4 waves (32x64 each), LDS dbuf 48KB -> 2 blocks/CU
__global__ __launch_bounds__(256) void k_gemm_mfma(const ushort* __restrict__ Vp,
                                                   const ushort* __restrict__ ZF,
                                                   float* __restrict__ S) {
  __shared__ ushort lds[24576];  // 2 bufs x (16KB A + 8KB B)
  const int t = threadIdx.x;
  const int w = t >> 6, l = t & 63;
  const int l15 = l & 15, l16 = l >> 4;
  const int col0 = blockIdx.x * 64, row0 = blockIdx.y * 128;
  const int cb4 = blockIdx.x * 4;

  // A-gather bases for frag rows rt = w and w+4 (element offsets into padded Vp)
  int abase[2];
#pragma unroll
  for (int i = 0; i < 2; ++i) {
    int r = row0 + (w + i * 4) * 16 + l15;
    int b = r >> 10, h = (r >> 5) & 31, wc = r & 31;
    abase[i] = ((b * 34 + h + 1) * 34 + (wc + 1)) * 256 + l16 * 8;
  }

  floatx4 acc[2][4];
#pragma unroll
  for (int i = 0; i < 2; ++i)
#pragma unroll
    for (int j = 0; j < 4; ++j) acc[i][j] = (floatx4){0.f, 0.f, 0.f, 0.f};

  auto stage = [&](int buf, int kt) {
    int tap = kt >> 2, cin0 = (kt & 3) << 6;
    int koff = ((tap / 3 - 1) * 34 + (tap % 3 - 1)) * 256 + cin0;
    ushort* Ad = lds + buf * 12288;
    ushort* Bd = Ad + 8192;
#pragma unroll
    for (int ii = 0; ii < 4; ++ii) {
      int bi = w + ii * 4;              // s = bi>>3, rt = bi&7
      int s = bi >> 3;
      gl_lds16(Vp + abase[ii & 1] + koff + s * 32, Ad + bi * 512);
    }
#pragma unroll
    for (int ii = 0; ii < 2; ++ii) {
      int bj = w + ii * 4;              // s = bj>>2, ct = bj&3
      int s = bj >> 2, ct = bj & 3;
      gl_lds16(ZF + ((size_t)((kt * 2 + s) * 16 + cb4 + ct)) * 512 + l * 8,
               Bd + bj * 512);
    }
  };

  auto compute = [&](int buf) {
    const ushort* Ab = lds + buf * 12288;
    const ushort* Bb = Ab + 8192;
    bf16x8 a[2][2], b[2][4];
#pragma unroll
    for (int s = 0; s < 2; ++s) {
#pragma unroll
      for (int i = 0; i < 2; ++i)
        a[s][i] = *(const bf16x8*)(Ab + (s * 8 + w * 2 + i) * 512 + l * 8);
#pragma unroll
      for (int j = 0; j < 4; ++j)
        b[s][j] = *(const bf16x8*)(Bb + (s * 4 + j) * 512 + l * 8);
    }
#pragma unroll
    for (int s = 0; s < 2; ++s)
#pragma unroll
      for (int i = 0; i < 2; ++i)
#pragma unroll
        for (int j = 0; j < 4; ++j)
          acc[i][j] = __builtin_amdgcn_mfma_f32_16x16x32_bf16(a[s][i], b[s][j],
                                                              acc[i][j], 0, 0, 0);
  };

  stage(0, 0);
  for (int kt = 0; kt < 36; ++kt) {
    __syncthreads();                 // drains stage(kt), joins compute(kt-1)
    if (kt + 1 < 36) stage((kt + 1) & 1, kt + 1);
    compute(kt & 1);
  }

#pragma unroll
  for (int i = 0; i < 2; ++i) {
    int r = row0 + w * 32 + i * 16 + l16 * 4;
#pragma unroll
    for (int j = 0; j < 4; ++j) {
      int c = col0 + j * 16 + l15;
#pragma unroll
      for (int reg = 0; reg < 4; ++reg)
        S[(size_t)(r + reg) * 256 + c] = acc[i][j][reg];
    }
  }
}

// ---------------------------------------------------------------- Poincare-FC epilogue
__global__ __launch_bounds__(256) void k_fcepi(const float* __restrict__ S,
                                               const float* __restrict__ P2,
                                               const float* __restrict__ ZN2,
                                               float* __restrict__ Hout) {
  int pix = blockIdx.x * 4 + (threadIdx.x >> 6);
  int lane = threadIdx.x & 63;
  float4 sv = ((const float4*)S)[pix * 64 + lane];
  float4 z2 = ((const float4*)ZN2)[lane];
  float p2 = P2[pix];
  float np = sqrtf(fmaxf(p2, EPSF));
  float un = tanhf(np);
  float f = un / np;
  if (un > MAXNRM) f *= MAXNRM / un;
  float u2 = f * f * p2;
  float lam = 2.f / fmaxf(1.f - u2, EPSF);
  float lf = lam * f;
  float zn[4] = {sqrtf(fmaxf(z2.x, EPSF)), sqrtf(fmaxf(z2.y, EPSF)),
                 sqrtf(fmaxf(z2.z, EPSF)), sqrtf(fmaxf(z2.w, EPSF))};
  float sval[4] = {sv.x, sv.y, sv.z, sv.w};
  float y[4];
#pragma unroll
  for (int k = 0; k < 4; ++k) {
    float d = 2.f * zn[k] * asinhf(lf * sval[k] / zn[k]);
    y[k] = sinhf(d);
  }
  float y2 = wred(y[0] * y[0] + y[1] * y[1] + y[2] * y[2] + y[3] * y[3]);
  float inv = 1.f / (1.f + sqrtf(1.f + y2));
  ((float4*)Hout)[pix * 64 + lane] =
      make_float4(y[0] * inv, y[1] * inv, y[2] * inv, y[3] * inv);
}

// ---------------------------------------------------------------- BN reduction 1
__global__ __launch_bounds__(256) void k_bnred1(const float* __restrict__ Hin,
                                                float* __restrict__ NUM,
                                                float* __restrict__ DEN) {
  __shared__ float snum[256];
  __shared__ float sden;
  int t = threadIdx.x;
  snum[t] = 0.f;
  if (t == 0) sden = 0.f;
  __syncthreads();
  int lane = t & 63, wv = t >> 6;
  float4 acc = make_float4(0.f, 0.f, 0.f, 0.f);
  float accd = 0.f;
  for (int it = 0; it < 32; ++it) {
    int pix = blockIdx.x * 128 + it * 4 + wv;
    float4 hv = ((const float4*)Hin)[pix * 64 + lane];
    float n2 = wred(hv.x * hv.x + hv.y * hv.y + hv.z * hv.z + hv.w * hv.w);
    float lam = 2.f / fmaxf(1.f - n2, EPSF);
    acc.x = fmaf(lam, hv.x, acc.x);
    acc.y = fmaf(lam, hv.y, acc.y);
    acc.z = fmaf(lam, hv.z, acc.z);
    acc.w = fmaf(lam, hv.w, acc.w);
    if (lane == 0) accd += lam - 1.f;
  }
  atomicAdd(&snum[lane * 4 + 0], acc.x);
  atomicAdd(&snum[lane * 4 + 1], acc.y);
  atomicAdd(&snum[lane * 4 + 2], acc.z);
  atomicAdd(&snum[lane * 4 + 3], acc.w);
  if (lane == 0) atomicAdd(&sden, accd);
  __syncthreads();
  atomicAdd(&NUM[t], snum[t]);
  if (t == 0) atomicAdd(DEN, sden);
}

// ---------------------------------------------------------------- BN midpoint + scalars
__global__ __launch_bounds__(256) void k_bnmid(const float* __restrict__ NUM,
                                               const float* __restrict__ DEN,
                                               const float* __restrict__ BIAS,
                                               float* __restrict__ MU,
                                               float* __restrict__ SCAL) {
  __shared__ float sb[4];
  int t = threadIdx.x, lane = t & 63, wv = t >> 6;
  auto bred = [&](float v) {
    v = wred(v);
    __syncthreads();
    if (lane == 0) sb[wv] = v;
    __syncthreads();
    return sb[0] + sb[1] + sb[2] + sb[3];
  };
  float m = NUM[t] / fmaxf(DEN[0], EPSF);
  float n2m = bred(m * m);
  float n = sqrtf(fmaxf(n2m, EPSF));
  float midf = tanhf(0.5f * atanhf(fminf(n, CLIP1))) / n;
  float mu = m * midf;
  MU[t] = mu;
  float bv = BIAS[t];
  float bias2 = bred(bv * bv);
  float mubias = bred(bv * mu);
  if (t == 0) {
    float mu2 = midf * midf * n2m;
    SCAL[0] = mu2;
    SCAL[1] = 2.f / fmaxf(1.f - mu2, EPSF);
    SCAL[2] = bias2;
    SCAL[3] = 2.f / fmaxf(1.f - bias2, EPSF);
    SCAL[4] = mubias;
  }
}

// ---------------------------------------------------------------- BN reduction 2 (var)
__global__ __launch_bounds__(256) void k_bnred2(const float* __restrict__ Hin,
                                                const float* __restrict__ MU,
                                                const float* __restrict__ SCAL,
                                                float* __restrict__ VAR) {
  __shared__ float sp[4];
  int t = threadIdx.x, lane = t & 63, wv = t >> 6;
  int pix = blockIdx.x * 4 + wv;
  float4 hv = ((const float4*)Hin)[pix * 64 + lane];
  float4 muv = ((const float4*)MU)[lane];
  float mu2 = SCAL[0];
  float x2 = wred(hv.x * hv.x + hv.y * hv.y + hv.z * hv.z + hv.w * hv.w);
  float xmu = wred(hv.x * muv.x + hv.y * muv.y + hv.z * muv.z + hv.w * muv.w);
  float A = 1.f - 2.f * xmu + mu2;
  float B = 1.f - x2;
  float num2 = A * A * x2 + B * B * mu2 - 2.f * A * B * xmu;
  float den = fmaxf(1.f - 2.f * xmu + x2 * mu2, EPSF);
  float nn = sqrtf(fmaxf(num2 / (den * den), EPSF));
  float dist = 2.f * atanhf(fminf(nn, CLIP1));
  float d2 = dist * dist;
  if (lane == 0) sp[wv] = d2;
  __syncthreads();
  if (t == 0) atomicAdd(VAR, sp[0] + sp[1] + sp[2] + sp[3]);
}

// ---------------------------------------------------------------- BN transform (+relu / +residual)
template <int PATH>
__global__ __launch_bounds__(256) void k_bntrans(const float* __restrict__ Hin,
                                                 const float* __restrict__ MU,
                                                 const float* __restrict__ SCAL,
                                                 const float* __restrict__ BIAS,
                                                 const float* __restrict__ WEIGHT,
                                                 const float* __restrict__ VAR,
                                                 const float* __restrict__ RES,
                                                 float* __restrict__ OUT) {
  int pix = blockIdx.x * 4 + (threadIdx.x >> 6);
  int lane = threadIdx.x & 63;
  float4 xv4 = ((const float4*)Hin)[pix * 64 + lane];
  float4 mu4 = ((const float4*)MU)[lane];
  float4 bb4 = ((const float4*)BIAS)[lane];
  float mu2 = SCAL[0], lam_mu = SCAL[1], bias2 = SCAL[2], lam_bias = SCAL[3],
        mubias = SCAL[4];
  float var = VAR[0] * (1.f / 16384.f);
  float rstd = sqrtf(WEIGHT[0] / fmaxf(var, EPSF));
  float x[4] = {xv4.x, xv4.y, xv4.z, xv4.w};
  float mm[4] = {mu4.x, mu4.y, mu4.z, mu4.w};
  float bs[4] = {bb4.x, bb4.y, bb4.z, bb4.w};
  float x2 = wred(x[0] * x[0] + x[1] * x[1] + x[2] * x[2] + x[3] * x[3]);
  float xmu = wred(x[0] * mm[0] + x[1] * mm[1] + x[2] * mm[2] + x[3] * mm[3]);
  float P = 1.f - 2.f * xmu + x2, Q = 1.f - mu2;
  float den1i = 1.f / fmaxf(1.f - 2.f * xmu + mu2 * x2, EPSF);
  float d[4];
#pragma unroll
  for (int k = 0; k < 4; ++k) d[k] = (Q * x[k] - P * mm[k]) * den1i;
  float nd2 = wred(d[0] * d[0] + d[1] * d[1] + d[2] * d[2] + d[3] * d[3]);
  float nd = sqrtf(fmaxf(nd2, EPSF));
  float vfac = (2.f / lam_mu) * atanhf(fminf(nd, CLIP1)) / nd;
  float v[4];
#pragma unroll
  for (int k = 0; k < 4; ++k) v[k] = vfac * d[k];
  float uw = wred(bs[0] * v[0] + bs[1] * v[1] + bs[2] * v[2] + bs[3] * v[3]);
  float mv = wred(mm[0] * v[0] + mm[1] * v[1] + mm[2] * v[2] + mm[3] * v[3]);
  float vw = -mv, uv = -mubias;
  float ga = -(uw * mu2) - vw + 2.f * uv * vw;
  float gb = -(vw * bias2) + uw;
  float ddi = 1.f / fmaxf(1.f + 2.f * uv + bias2 * mu2, EPSF);
  float sgy = (lam_mu / lam_bias) * rstd;
  float u[4];
#pragma unroll
  for (int k = 0; k < 4; ++k)
    u[k] = (v[k] + 2.f * (ga * bs[k] - gb * mm[k]) * ddi) * sgy;
  float nu2 = wred(u[0] * u[0] + u[1] * u[1] + u[2] * u[2] + u[3] * u[3]);
  float bu = wred(bs[0] * u[0] + bs[1] * u[1] + bs[2] * u[2] + bs[3] * u[3]);
  float nu = sqrtf(fmaxf(nu2, EPSF));
  float sfac = tanhf(lam_bias * nu * 0.5f) / nu;
  float y2 = sfac * sfac * nu2, xy = sfac * bu;
  float P2 = 1.f + 2.f * xy + y2, Q2 = 1.f - bias2;
  float den2i = 1.f / fmaxf(1.f + 2.f * xy + bias2 * y2, EPSF);
  float r[4];
#pragma unroll
  for (int k = 0; k < 4; ++k) r[k] = (P2 * bs[k] + Q2 * sfac * u[k]) * den2i;
  float nr2 = wred(r[0] * r[0] + r[1] * r[1] + r[2] * r[2] + r[3] * r[3]);
  float nr = sqrtf(fmaxf(nr2, EPSF));
  if (nr > MAXNRM) {
    float sc = MAXNRM / nr;
#pragma unroll
    for (int k = 0; k < 4; ++k) r[k] *= sc;
    nr = MAXNRM;
  }
  if (PATH == 2) {
    float h2 = nr * nr;
    float4 rs4 = ((const float4*)RES)[pix * 64 + lane];
    float rr[4] = {rs4.x, rs4.y, rs4.z, rs4.w};
    float y2r = wred(rr[0] * rr[0] + rr[1] * rr[1] + rr[2] * rr[2] + rr[3] * rr[3]);
    float xyr = wred(r[0] * rr[0] + r[1] * rr[1] + r[2] * rr[2] + r[3] * rr[3]);
    float Pm = 1.f + 2.f * xyr + y2r, Qm = 1.f - h2;
    float denmi = 1.f / fmaxf(1.f + 2.f * xyr + h2 * y2r, EPSF);
#pragma unroll
    for (int k = 0; k < 4; ++k) r[k] = (Pm * r[k] + Qm * rr[k]) * denmi;
    nr2 = wred(r[0] * r[0] + r[1] * r[1] + r[2] * r[2] + r[3] * r[3]);
    nr = sqrtf(fmaxf(nr2, EPSF));
  }
  float tf = atanhf(fminf(nr, CLIP1)) / nr;
  float tr[4];
#pragma unroll
  for (int k = 0; k < 4; ++k) tr[k] = fmaxf(tf * r[k], 0.f);
  float nt2 = wred(tr[0] * tr[0] + tr[1] * tr[1] + tr[2] * tr[2] + tr[3] * tr[3]);
  float nt = sqrtf(fmaxf(nt2, EPSF));
  float une = tanhf(nt);
  float ef = une / nt;
  if (une > MAXNRM) ef *= MAXNRM / une;
  ((float4*)OUT)[pix * 64 + lane] =
      make_float4(ef * tr[0], ef * tr[1], ef * tr[2], ef * tr[3]);
}

// ---------------------------------------------------------------- [N,C] -> [B,C,H,W]
__global__ __launch_bounds__(256) void k_outT(const float* __restrict__ Src,
                                              float* __restrict__ Out) {
  __shared__ float tile[256 * 33];
  int b = blockIdx.x >> 5, h = blockIdx.x & 31;
  int t = threadIdx.x;
  int pix0 = blockIdx.x * 32;
  int g = t & 63;
#pragma unroll
  for (int it = 0; it < 8; ++it) {
    int p = (t >> 6) + it * 4;
    float4 v = ((const float4*)Src)[(size_t)(pix0 + p) * 64 + g];
    tile[(g * 4 + 0) * 33 + p] = v.x;
    tile[(g * 4 + 1) * 33 + p] = v.y;
    tile[(g * 4 + 2) * 33 + p] = v.z;
    tile[(g * 4 + 3) * 33 + p] = v.w;
  }
  __syncthreads();
  for (int c0 = 0; c0 < 256; c0 += 8) {
    int c = c0 + (t >> 5), w = t & 31;
    Out[((b * 256 + c) * 32 + h) * 32 + w] = tile[c * 33 + w];
  }
}

// ---------------------------------------------------------------- launch
extern "C" void kernel_launch(void* const* d_in, const int* in_sizes, int n_in,
                              void* d_out, int out_size, void* d_ws, size_t ws_size,
                              hipStream_t stream) {
  (void)in_sizes; (void)n_in; (void)out_size; (void)ws_size;
  const float* x  = (const float*)d_in[0];
  const float* z1 = (const float*)d_in[1];
  const float* z2 = (const float*)d_in[2];
  const float* w1 = (const float*)d_in[3];
  const float* b1 = (const float*)d_in[4];
  const float* w2 = (const float*)d_in[5];
  const float* b2 = (const float*)d_in[6];
  float* out = (float*)d_out;
  float* ws = (float*)d_ws;

  float* zn2  = ws;          // 512
  float* num  = ws + 512;    // 256
  float* den  = ws + 768;    // 1
  float* var  = ws + 769;    // 1
  float* mu   = ws + 772;    // 256
  float* scal = ws + 1028;   // 8
  float* nv2  = ws + 2048;          // 16384
  float* p2   = ws + 2048 + 16384;  // 16384
  float* xl   = ws + 34816;         // 16 MB
  float* h    = xl + 4194304;       // 16 MB
  float* s    = h + 4194304;        // 16 MB
  ushort* Vp  = (ushort*)(s + 4194304);  // 16*34*34*256 bf16 = 9.47 MB
  ushort* ZF  = Vp + 4734976;            // 2 x 589824 bf16 = 2.36 MB

  double lb = (lgamma(1152.0) - lgamma(1152.5)) - (lgamma(128.0) - lgamma(128.5));
  float scale = (float)exp(lb);

  hipMemsetAsync(ws, 0, 2048 * sizeof(float), stream);
  hipMemsetAsync(Vp, 0, (size_t)4734976 * 2, stream);  // zero padding borders
  k_zpack<<<dim3(72, 2), 256, 0, stream>>>(z1, z2, ZF, zn2);

  // ---- conv1
  k_pre1<<<512, 256, 0, stream>>>(x, xl, Vp, nv2, scale);
  k_boxsum<<<64, 256, 0, stream>>>(nv2, p2);
  k_gemm_mfma<<<dim3(4, 128), 256, 0, stream>>>(Vp, ZF, s);
  k_fcepi<<<4096, 256, 0, stream>>>(s, p2, zn2, h);
  // ---- bn1 + relu (in place)
  k_bnred1<<<128, 256, 0, stream>>>(h, num, den);
  k_bnmid<<<1, 256, 0, stream>>>(num, den, b1, mu, scal);
  k_bnred2<<<4096, 256, 0, stream>>>(h, mu, scal, var);
  k_bntrans<1><<<4096, 256, 0, stream>>>(h, mu, scal, b1, w1, var, xl, h);

  // ---- conv2
  hipMemsetAsync(num, 0, 258 * sizeof(float), stream);  // num,den,var
  k_preB<<<4096, 256, 0, stream>>>(h, Vp, nv2, scale);
  k_boxsum<<<64, 256, 0, stream>>>(nv2, p2);
  k_gemm_mfma<<<dim3(4, 128), 256, 0, stream>>>(Vp, ZF + 589824, s);
  k_fcepi<<<4096, 256, 0, stream>>>(s, p2, zn2 + 256, h);
  // ---- bn2 + residual + relu -> s (channel-last), then transpose
  k_bnred1<<<128, 256, 0, stream>>>(h, num, den);
  k_bnmid<<<1, 256, 0, stream>>>(num, den, b2, mu, scal);
  k_bnred2<<<4096, 256, 0, stream>>>(h, mu, scal, var);
  k_bntrans<2><<<4096, 256, 0, stream>>>(h, mu, scal, b2, w2, var, xl, s);
  k_outT<<<512, 256, 0, stream>>>(s, out);
}

// Round 4
// 398.637 us; speedup vs baseline: 3.6847x; 1.2202x over previous
//
#include <hip/hip_runtime.h>
#include <math.h>

#define EPSF   1e-15f
#define CLIP1  0.99999988f   /* fp32(1 - 1e-7) */
#define MAXNRM 0.99999f      /* (1 - 1e-5)/sqrt(c), c = 1 */

typedef __bf16 bf16x8 __attribute__((ext_vector_type(8)));
typedef float floatx4 __attribute__((ext_vector_type(4)));

// ---------------------------------------------------------------- utilities
__device__ __forceinline__ float wred(float x) {
#pragma unroll
  for (int o = 32; o; o >>= 1) x += __shfl_xor(x, o);
  return x;
}

__device__ __forceinline__ unsigned short f2bf(float f) {
  unsigned int u = __float_as_uint(f);
  u += 0x7fffu + ((u >> 16) & 1u);   // RNE
  return (unsigned short)(u >> 16);
}

__device__ __forceinline__ void gl_lds16(const ushort* g, ushort* l) {
  __builtin_amdgcn_global_load_lds(
      (const __attribute__((address_space(1))) void*)g,
      (__attribute__((address_space(3))) void*)l, 16, 0, 0);
}

// ---------------------------------------------------------------- Z -> fragment-ordered bf16 (+ column norms^2)
// ZF block index (kt*16 + ctg), 1KB each: lane l, j: Z[kt*32+(l>>4)*8+j][ctg*16+(l&15)]
__global__ __launch_bounds__(256) void k_zpack(const float* __restrict__ Z1,
                                               const float* __restrict__ Z2,
                                               ushort* __restrict__ ZF,
                                               float* __restrict__ ZN2) {
  __shared__ float zs[32 * 256];
  int kt = blockIdx.x, mat = blockIdx.y;
  const float* Z = mat ? Z2 : Z1;
  ushort* out = ZF + (size_t)mat * 589824;
  int t = threadIdx.x;
  const float4* src = (const float4*)(Z + kt * 32 * 256);
  float4* dst4 = (float4*)zs;
#pragma unroll
  for (int i = 0; i < 8; ++i) dst4[t + i * 256] = src[t + i * 256];
  __syncthreads();
  // fused column-norm^2 partial (replaces k_znorm)
  {
    float acc = 0.f;
#pragma unroll 8
    for (int k = 0; k < 32; ++k) {
      float z = zs[k * 256 + t];
      acc = fmaf(z, z, acc);
    }
    atomicAdd(&ZN2[mat * 256 + t], acc);
  }
  int l = t & 63, sub = t >> 6;
  for (int i = 0; i < 4; ++i) {
    int combo = sub * 4 + i;                 // ctg 0..15
    int col = combo * 16 + (l & 15);
    int krow = (l >> 4) * 8;
    unsigned int pk[4];
#pragma unroll
    for (int j = 0; j < 4; ++j) {
      unsigned int lo = f2bf(zs[(krow + 2 * j) * 256 + col]);
      unsigned int hi = f2bf(zs[(krow + 2 * j + 1) * 256 + col]);
      pk[j] = lo | (hi << 16);
    }
    uint4* o = (uint4*)(out + ((size_t)(kt * 16 + combo)) * 512 + l * 8);
    *o = make_uint4(pk[0], pk[1], pk[2], pk[3]);
  }
}

// ---------------------------------------------------------------- x[B,C,H,W] -> xl fp32, Vp bf16(padded), nv2
__global__ __launch_bounds__(256) void k_pre1(const float* __restrict__ X,
                                              float* __restrict__ XL,
                                              ushort* __restrict__ Vp,
                                              float* __restrict__ NV2,
                                              float scale) {
  __shared__ float tile[256 * 33];
  __shared__ float facs[32];
  const int b = blockIdx.x >> 5, h = blockIdx.x & 31;
  const int t = threadIdx.x;
  for (int c0 = 0; c0 < 256; c0 += 8) {
    int c = c0 + (t >> 5), w = t & 31;
    tile[c * 33 + w] = X[((b * 256 + c) * 32 + h) * 32 + w];
  }
  __syncthreads();
  {
    int w = t >> 3, s = t & 7;
    float n2 = 0.f;
#pragma unroll 8
    for (int i = 0; i < 32; ++i) {
      float xv = tile[(s + 8 * i) * 33 + w];
      n2 = fmaf(xv, xv, n2);
    }
    n2 += __shfl_xor(n2, 1); n2 += __shfl_xor(n2, 2); n2 += __shfl_xor(n2, 4);
    float n = sqrtf(fmaxf(n2, EPSF));
    float fac = atanhf(fminf(n, CLIP1)) / n * scale;
    if (s == 0) {
      facs[w] = fac;
      NV2[blockIdx.x * 32 + w] = fac * fac * n2;
    }
  }
  __syncthreads();
  const int g = t & 63;
  const int pix0 = blockIdx.x * 32;
#pragma unroll
  for (int it = 0; it < 8; ++it) {
    int p = (t >> 6) + it * 4;
    float f = facs[p];
    float4 val;
    val.x = tile[(g * 4 + 0) * 33 + p];
    val.y = tile[(g * 4 + 1) * 33 + p];
    val.z = tile[(g * 4 + 2) * 33 + p];
    val.w = tile[(g * 4 + 3) * 33 + p];
    *(float4*)(XL + (size_t)(pix0 + p) * 256 + g * 4) = val;
    ushort4 vb;
    vb.x = f2bf(val.x * f); vb.y = f2bf(val.y * f);
    vb.z = f2bf(val.z * f); vb.w = f2bf(val.w * f);
    *(ushort4*)(Vp + ((size_t)((b * 34 + h + 1) * 34 + (p + 1))) * 256 + g * 4) = vb;
  }
}

// ---------------------------------------------------------------- h[N,C] -> Vp bf16(padded), nv2
__global__ __launch_bounds__(256) void k_preB(const float* __restrict__ Hin,
                                              ushort* __restrict__ Vp,
                                              float* __restrict__ NV2,
                                              float scale) {
  int pix = blockIdx.x * 4 + (threadIdx.x >> 6);
  int lane = threadIdx.x & 63;
  float4 hv = ((const float4*)Hin)[pix * 64 + lane];
  float n2 = wred(hv.x * hv.x + hv.y * hv.y + hv.z * hv.z + hv.w * hv.w);
  float n = sqrtf(fmaxf(n2, EPSF));
  float fac = atanhf(fminf(n, CLIP1)) / n * scale;
  int b = pix >> 10, hh = (pix >> 5) & 31, ww = pix & 31;
  ushort4 vb;
  vb.x = f2bf(hv.x * fac); vb.y = f2bf(hv.y * fac);
  vb.z = f2bf(hv.z * fac); vb.w = f2bf(hv.w * fac);
  *(ushort4*)(Vp + ((size_t)((b * 34 + hh + 1) * 34 + (ww + 1))) * 256 + lane * 4) = vb;
  if (lane == 0) NV2[pix] = fac * fac * n2;
}

// ---------------------------------------------------------------- 3x3 box sum of nv2
__global__ __launch_bounds__(256) void k_boxsum(const float* __restrict__ NV2,
                                                float* __restrict__ P2) {
  int pix = blockIdx.x * 256 + threadIdx.x;
  int hw = pix & 1023, hh = hw >> 5, ww = hw & 31, base = pix & ~1023;
  float s = 0.f;
#pragma unroll
  for (int di = -1; di <= 1; ++di)
#pragma unroll
    for (int dj = -1; dj <= 1; ++dj) {
      int sh = hh + di, sw = ww + dj;
      if ((unsigned)sh < 32u && (unsigned)sw < 32u) s += NV2[base + sh * 32 + sw];
    }
  P2[pix] = s;
}

// ---------------------------------------------------------------- MFMA implicit-GEMM conv
// S[16384,256] = im2col(Vp)[16384,2304] @ Z[2304,256], bf16 in, fp32 out
// tile 128 rows x 64 cols, BK=64, 4 waves (32x64 each), LDS dbuf 48KB -> 2 blocks/CU
__global__ __launch_bounds__(256) void k_gemm_mfma(const ushort* __restrict__ Vp,
                                                   const ushort* __restrict__ ZF,
                                                   float* __restrict__ S) {
  __shared__ ushort lds[24576];  // 2 bufs x (16KB A + 8KB B)
  const int t = threadIdx.x;
  const int w = t >> 6, l = t & 63;
  const int l15 = l & 15, l16 = l >> 4;
  const int col0 = blockIdx.x * 64, row0 = blockIdx.y * 128;
  const int cb4 = blockIdx.x * 4;

  // A-gather bases for frag rows rt = w and w+4 (element offsets into padded Vp)
  int abase[2];
#pragma unroll
  for (int i = 0; i < 2; ++i) {
    int r = row0 + (w + i * 4) * 16 + l15;
    int b = r >> 10, h = (r >> 5) & 31, wc = r & 31;
    abase[i] = ((b * 34 + h + 1) * 34 + (wc + 1)) * 256 + l16 * 8;
  }

  floatx4 acc[2][4];
#pragma unroll
  for (int i = 0; i < 2; ++i)
#pragma unroll
    for (int j = 0; j < 4; ++j) acc[i][j] = (floatx4){0.f, 0.f, 0.f, 0.f};

  auto stage = [&](int buf, int kt) {
    int tap = kt >> 2, cin0 = (kt & 3) << 6;
    int koff = ((tap / 3 - 1) * 34 + (tap % 3 - 1)) * 256 + cin0;
    ushort* Ad = lds + buf * 12288;
    ushort* Bd = Ad + 8192;
#pragma unroll
    for (int ii = 0; ii < 4; ++ii) {
      int bi = w + ii * 4;              // s = bi>>3, rt = bi&7
      int s = bi >> 3;
      gl_lds16(Vp + abase[ii & 1] + koff + s * 32, Ad + bi * 512);
    }
#pragma unroll
    for (int ii = 0; ii < 2; ++ii) {
      int bj = w + ii * 4;              // s = bj>>2, ct = bj&3
      int s = bj >> 2, ct = bj & 3;
      gl_lds16(ZF + ((size_t)((kt * 2 + s) * 16 + cb4 + ct)) * 512 + l * 8,
               Bd + bj * 512);
    }
  };

  auto compute = [&](int buf) {
    const ushort* Ab = lds + buf * 12288;
    const ushort* Bb = Ab + 8192;
    bf16x8 a[2][2], b[2][4];
#pragma unroll
    for (int s = 0; s < 2; ++s) {
#pragma unroll
      for (int i = 0; i < 2; ++i)
        a[s][i] = *(const bf16x8*)(Ab + (s * 8 + w * 2 + i) * 512 + l * 8);
#pragma unroll
      for (int j = 0; j < 4; ++j)
        b[s][j] = *(const bf16x8*)(Bb + (s * 4 + j) * 512 + l * 8);
    }
#pragma unroll
    for (int s = 0; s < 2; ++s)
#pragma unroll
      for (int i = 0; i < 2; ++i)
#pragma unroll
        for (int j = 0; j < 4; ++j)
          acc[i][j] = __builtin_amdgcn_mfma_f32_16x16x32_bf16(a[s][i], b[s][j],
                                                              acc[i][j], 0, 0, 0);
  };

  stage(0, 0);
  for (int kt = 0; kt < 36; ++kt) {
    __syncthreads();                 // drains stage(kt), joins compute(kt-1)
    if (kt + 1 < 36) stage((kt + 1) & 1, kt + 1);
    compute(kt & 1);
  }

#pragma unroll
  for (int i = 0; i < 2; ++i) {
    int r = row0 + w * 32 + i * 16 + l16 * 4;
#pragma unroll
    for (int j = 0; j < 4; ++j) {
      int c = col0 + j * 16 + l15;
#pragma unroll
      for (int reg = 0; reg < 4; ++reg)
        S[(size_t)(r + reg) * 256 + c] = acc[i][j][reg];
    }
  }
}

// ---------------------------------------------------------------- Poincare-FC epilogue
__global__ __launch_bounds__(256) void k_fcepi(const float* __restrict__ S,
                                               const float* __restrict__ P2,
                                               const float* __restrict__ ZN2,
                                               float* __restrict__ Hout) {
  int pix = blockIdx.x * 4 + (threadIdx.x >> 6);
  int lane = threadIdx.x & 63;
  float4 sv = ((const float4*)S)[pix * 64 + lane];
  float4 z2 = ((const float4*)ZN2)[lane];
  float p2 = P2[pix];
  float np = sqrtf(fmaxf(p2, EPSF));
  float un = tanhf(np);
  float f = un / np;
  if (un > MAXNRM) f *= MAXNRM / un;
  float u2 = f * f * p2;
  float lam = 2.f / fmaxf(1.f - u2, EPSF);
  float lf = lam * f;
  float zn[4] = {sqrtf(fmaxf(z2.x, EPSF)), sqrtf(fmaxf(z2.y, EPSF)),
                 sqrtf(fmaxf(z2.z, EPSF)), sqrtf(fmaxf(z2.w, EPSF))};
  float sval[4] = {sv.x, sv.y, sv.z, sv.w};
  float y[4];
#pragma unroll
  for (int k = 0; k < 4; ++k) {
    float d = 2.f * zn[k] * asinhf(lf * sval[k] / zn[k]);
    y[k] = sinhf(d);
  }
  float y2 = wred(y[0] * y[0] + y[1] * y[1] + y[2] * y[2] + y[3] * y[3]);
  float inv = 1.f / (1.f + sqrtf(1.f + y2));
  ((float4*)Hout)[pix * 64 + lane] =
      make_float4(y[0] * inv, y[1] * inv, y[2] * inv, y[3] * inv);
}

// ---------------------------------------------------------------- BN reduction 1
__global__ __launch_bounds__(256) void k_bnred1(const float* __restrict__ Hin,
                                                float* __restrict__ NUM,
                                                float* __restrict__ DEN) {
  __shared__ float snum[256];
  __shared__ float sden;
  int t = threadIdx.x;
  snum[t] = 0.f;
  if (t == 0) sden = 0.f;
  __syncthreads();
  int lane = t & 63, wv = t >> 6;
  float4 acc = make_float4(0.f, 0.f, 0.f, 0.f);
  float accd = 0.f;
  for (int it = 0; it < 32; ++it) {
    int pix = blockIdx.x * 128 + it * 4 + wv;
    float4 hv = ((const float4*)Hin)[pix * 64 + lane];
    float n2 = wred(hv.x * hv.x + hv.y * hv.y + hv.z * hv.z + hv.w * hv.w);
    float lam = 2.f / fmaxf(1.f - n2, EPSF);
    acc.x = fmaf(lam, hv.x, acc.x);
    acc.y = fmaf(lam, hv.y, acc.y);
    acc.z = fmaf(lam, hv.z, acc.z);
    acc.w = fmaf(lam, hv.w, acc.w);
    if (lane == 0) accd += lam - 1.f;
  }
  atomicAdd(&snum[lane * 4 + 0], acc.x);
  atomicAdd(&snum[lane * 4 + 1], acc.y);
  atomicAdd(&snum[lane * 4 + 2], acc.z);
  atomicAdd(&snum[lane * 4 + 3], acc.w);
  if (lane == 0) atomicAdd(&sden, accd);
  __syncthreads();
  atomicAdd(&NUM[t], snum[t]);
  if (t == 0) atomicAdd(DEN, sden);
}

// ---------------------------------------------------------------- BN midpoint + scalars
__global__ __launch_bounds__(256) void k_bnmid(const float* __restrict__ NUM,
                                               const float* __restrict__ DEN,
                                               const float* __restrict__ BIAS,
                                               float* __restrict__ MU,
                                               float* __restrict__ SCAL) {
  __shared__ float sb[4];
  int t = threadIdx.x, lane = t & 63, wv = t >> 6;
  auto bred = [&](float v) {
    v = wred(v);
    __syncthreads();
    if (lane == 0) sb[wv] = v;
    __syncthreads();
    return sb[0] + sb[1] + sb[2] + sb[3];
  };
  float m = NUM[t] / fmaxf(DEN[0], EPSF);
  float n2m = bred(m * m);
  float n = sqrtf(fmaxf(n2m, EPSF));
  float midf = tanhf(0.5f * atanhf(fminf(n, CLIP1))) / n;
  float mu = m * midf;
  MU[t] = mu;
  float bv = BIAS[t];
  float bias2 = bred(bv * bv);
  float mubias = bred(bv * mu);
  if (t == 0) {
    float mu2 = midf * midf * n2m;
    SCAL[0] = mu2;
    SCAL[1] = 2.f / fmaxf(1.f - mu2, EPSF);
    SCAL[2] = bias2;
    SCAL[3] = 2.f / fmaxf(1.f - bias2, EPSF);
    SCAL[4] = mubias;
  }
}

// ---------------------------------------------------------------- BN reduction 2 (var)
// 128 blocks x 128 pixels: one same-address atomic per block (was 4096 -> 76us serial)
__global__ __launch_bounds__(256) void k_bnred2(const float* __restrict__ Hin,
                                                const float* __restrict__ MU,
                                                const float* __restrict__ SCAL,
                                                float* __restrict__ VAR) {
  __shared__ float sp[4];
  int t = threadIdx.x, lane = t & 63, wv = t >> 6;
  float4 muv = ((const float4*)MU)[lane];
  float mu2 = SCAL[0];
  float accd = 0.f;
  for (int it = 0; it < 32; ++it) {
    int pix = blockIdx.x * 128 + it * 4 + wv;
    float4 hv = ((const float4*)Hin)[pix * 64 + lane];
    float x2 = wred(hv.x * hv.x + hv.y * hv.y + hv.z * hv.z + hv.w * hv.w);
    float xmu = wred(hv.x * muv.x + hv.y * muv.y + hv.z * muv.z + hv.w * muv.w);
    float A = 1.f - 2.f * xmu + mu2;
    float B = 1.f - x2;
    float num2 = A * A * x2 + B * B * mu2 - 2.f * A * B * xmu;
    float den = fmaxf(1.f - 2.f * xmu + x2 * mu2, EPSF);
    float nn = sqrtf(fmaxf(num2 / (den * den), EPSF));
    float dist = 2.f * atanhf(fminf(nn, CLIP1));
    accd += dist * dist;
  }
  if (lane == 0) sp[wv] = accd;
  __syncthreads();
  if (t == 0) atomicAdd(VAR, sp[0] + sp[1] + sp[2] + sp[3]);
}

// ---------------------------------------------------------------- BN transform (+relu / +residual)
template <int PATH>
__global__ __launch_bounds__(256) void k_bntrans(const float* __restrict__ Hin,
                                                 const float* __restrict__ MU,
                                                 const float* __restrict__ SCAL,
                                                 const float* __restrict__ BIAS,
                                                 const float* __restrict__ WEIGHT,
                                                 const float* __restrict__ VAR,
                                                 const float* __restrict__ RES,
                                                 float* __restrict__ OUT) {
  int pix = blockIdx.x * 4 + (threadIdx.x >> 6);
  int lane = threadIdx.x & 63;
  float4 xv4 = ((const float4*)Hin)[pix * 64 + lane];
  float4 mu4 = ((const float4*)MU)[lane];
  float4 bb4 = ((const float4*)BIAS)[lane];
  float mu2 = SCAL[0], lam_mu = SCAL[1], bias2 = SCAL[2], lam_bias = SCAL[3],
        mubias = SCAL[4];
  float var = VAR[0] * (1.f / 16384.f);
  float rstd = sqrtf(WEIGHT[0] / fmaxf(var, EPSF));
  float x[4] = {xv4.x, xv4.y, xv4.z, xv4.w};
  float mm[4] = {mu4.x, mu4.y, mu4.z, mu4.w};
  float bs[4] = {bb4.x, bb4.y, bb4.z, bb4.w};
  float x2 = wred(x[0] * x[0] + x[1] * x[1] + x[2] * x[2] + x[3] * x[3]);
  float xmu = wred(x[0] * mm[0] + x[1] * mm[1] + x[2] * mm[2] + x[3] * mm[3]);
  float P = 1.f - 2.f * xmu + x2, Q = 1.f - mu2;
  float den1i = 1.f / fmaxf(1.f - 2.f * xmu + mu2 * x2, EPSF);
  float d[4];
#pragma unroll
  for (int k = 0; k < 4; ++k) d[k] = (Q * x[k] - P * mm[k]) * den1i;
  float nd2 = wred(d[0] * d[0] + d[1] * d[1] + d[2] * d[2] + d[3] * d[3]);
  float nd = sqrtf(fmaxf(nd2, EPSF));
  float vfac = (2.f / lam_mu) * atanhf(fminf(nd, CLIP1)) / nd;
  float v[4];
#pragma unroll
  for (int k = 0; k < 4; ++k) v[k] = vfac * d[k];
  float uw = wred(bs[0] * v[0] + bs[1] * v[1] + bs[2] * v[2] + bs[3] * v[3]);
  float mv = wred(mm[0] * v[0] + mm[1] * v[1] + mm[2] * v[2] + mm[3] * v[3]);
  float vw = -mv, uv = -mubias;
  float ga = -(uw * mu2) - vw + 2.f * uv * vw;
  float gb = -(vw * bias2) + uw;
  float ddi = 1.f / fmaxf(1.f + 2.f * uv + bias2 * mu2, EPSF);
  float sgy = (lam_mu / lam_bias) * rstd;
  float u[4];
#pragma unroll
  for (int k = 0; k < 4; ++k)
    u[k] = (v[k] + 2.f * (ga * bs[k] - gb * mm[k]) * ddi) * sgy;
  float nu2 = wred(u[0] * u[0] + u[1] * u[1] + u[2] * u[2] + u[3] * u[3]);
  float bu = wred(bs[0] * u[0] + bs[1] * u[1] + bs[2] * u[2] + bs[3] * u[3]);
  float nu = sqrtf(fmaxf(nu2, EPSF));
  float sfac = tanhf(lam_bias * nu * 0.5f) / nu;
  float y2 = sfac * sfac * nu2, xy = sfac * bu;
  float P2 = 1.f + 2.f * xy + y2, Q2 = 1.f - bias2;
  float den2i = 1.f / fmaxf(1.f + 2.f * xy + bias2 * y2, EPSF);
  float r[4];
#pragma unroll
  for (int k = 0; k < 4; ++k) r[k] = (P2 * bs[k] + Q2 * sfac * u[k]) * den2i;
  float nr2 = wred(r[0] * r[0] + r[1] * r[1] + r[2] * r[2] + r[3] * r[3]);
  float nr = sqrtf(fmaxf(nr2, EPSF));
  if (nr > MAXNRM) {
    float sc = MAXNRM / nr;
#pragma unroll
    for (int k = 0; k < 4; ++k) r[k] *= sc;
    nr = MAXNRM;
  }
  if (PATH == 2) {
    float h2 = nr * nr;
    float4 rs4 = ((const float4*)RES)[pix * 64 + lane];
    float rr[4] = {rs4.x, rs4.y, rs4.z, rs4.w};
    float y2r = wred(rr[0] * rr[0] + rr[1] * rr[1] + rr[2] * rr[2] + rr[3] * rr[3]);
    float xyr = wred(r[0] * rr[0] + r[1] * rr[1] + r[2] * rr[2] + r[3] * rr[3]);
    float Pm = 1.f + 2.f * xyr + y2r, Qm = 1.f - h2;
    float denmi = 1.f / fmaxf(1.f + 2.f * xyr + h2 * y2r, EPSF);
#pragma unroll
    for (int k = 0; k < 4; ++k) r[k] = (Pm * r[k] + Qm * rr[k]) * denmi;
    nr2 = wred(r[0] * r[0] + r[1] * r[1] + r[2] * r[2] + r[3] * r[3]);
    nr = sqrtf(fmaxf(nr2, EPSF));
  }
  float tf = atanhf(fminf(nr, CLIP1)) / nr;
  float tr[4];
#pragma unroll
  for (int k = 0; k < 4; ++k) tr[k] = fmaxf(tf * r[k], 0.f);
  float nt2 = wred(tr[0] * tr[0] + tr[1] * tr[1] + tr[2] * tr[2] + tr[3] * tr[3]);
  float nt = sqrtf(fmaxf(nt2, EPSF));
  float une = tanhf(nt);
  float ef = une / nt;
  if (une > MAXNRM) ef *= MAXNRM / une;
  ((float4*)OUT)[pix * 64 + lane] =
      make_float4(ef * tr[0], ef * tr[1], ef * tr[2], ef * tr[3]);
}

// ---------------------------------------------------------------- [N,C] -> [B,C,H,W]
__global__ __launch_bounds__(256) void k_outT(const float* __restrict__ Src,
                                              float* __restrict__ Out) {
  __shared__ float tile[256 * 33];
  int b = blockIdx.x >> 5, h = blockIdx.x & 31;
  int t = threadIdx.x;
  int pix0 = blockIdx.x * 32;
  int g = t & 63;
#pragma unroll
  for (int it = 0; it < 8; ++it) {
    int p = (t >> 6) + it * 4;
    float4 v = ((const float4*)Src)[(size_t)(pix0 + p) * 64 + g];
    tile[(g * 4 + 0) * 33 + p] = v.x;
    tile[(g * 4 + 1) * 33 + p] = v.y;
    tile[(g * 4 + 2) * 33 + p] = v.z;
    tile[(g * 4 + 3) * 33 + p] = v.w;
  }
  __syncthreads();
  for (int c0 = 0; c0 < 256; c0 += 8) {
    int c = c0 + (t >> 5), w = t & 31;
    Out[((b * 256 + c) * 32 + h) * 32 + w] = tile[c * 33 + w];
  }
}

// ---------------------------------------------------------------- launch
extern "C" void kernel_launch(void* const* d_in, const int* in_sizes, int n_in,
                              void* d_out, int out_size, void* d_ws, size_t ws_size,
                              hipStream_t stream) {
  (void)in_sizes; (void)n_in; (void)out_size; (void)ws_size;
  const float* x  = (const float*)d_in[0];
  const float* z1 = (const float*)d_in[1];
  const float* z2 = (const float*)d_in[2];
  const float* w1 = (const float*)d_in[3];
  const float* b1 = (const float*)d_in[4];
  const float* w2 = (const float*)d_in[5];
  const float* b2 = (const float*)d_in[6];
  float* out = (float*)d_out;
  float* ws = (float*)d_ws;

  float* zn2  = ws;          // 512
  float* num  = ws + 512;    // 256
  float* den  = ws + 768;    // 1
  float* var  = ws + 769;    // 1
  float* mu   = ws + 772;    // 256
  float* scal = ws + 1028;   // 8
  float* nv2  = ws + 2048;          // 16384
  float* p2   = ws + 2048 + 16384;  // 16384
  float* xl   = ws + 34816;         // 16 MB
  float* h    = xl + 4194304;       // 16 MB
  float* s    = h + 4194304;        // 16 MB
  ushort* Vp  = (ushort*)(s + 4194304);  // 16*34*34*256 bf16 = 9.47 MB
  ushort* ZF  = Vp + 4734976;            // 2 x 589824 bf16 = 2.36 MB

  double lb = (lgamma(1152.0) - lgamma(1152.5)) - (lgamma(128.0) - lgamma(128.5));
  float scale = (float)exp(lb);

  hipMemsetAsync(ws, 0, 2048 * sizeof(float), stream);
  hipMemsetAsync(Vp, 0, (size_t)4734976 * 2, stream);  // zero padding borders
  k_zpack<<<dim3(72, 2), 256, 0, stream>>>(z1, z2, ZF, zn2);

  // ---- conv1
  k_pre1<<<512, 256, 0, stream>>>(x, xl, Vp, nv2, scale);
  k_boxsum<<<64, 256, 0, stream>>>(nv2, p2);
  k_gemm_mfma<<<dim3(4, 128), 256, 0, stream>>>(Vp, ZF, s);
  k_fcepi<<<4096, 256, 0, stream>>>(s, p2, zn2, h);
  // ---- bn1 + relu (in place)
  k_bnred1<<<128, 256, 0, stream>>>(h, num, den);
  k_bnmid<<<1, 256, 0, stream>>>(num, den, b1, mu, scal);
  k_bnred2<<<128, 256, 0, stream>>>(h, mu, scal, var);
  k_bntrans<1><<<4096, 256, 0, stream>>>(h, mu, scal, b1, w1, var, xl, h);

  // ---- conv2
  hipMemsetAsync(num, 0, 258 * sizeof(float), stream);  // num,den,var
  k_preB<<<4096, 256, 0, stream>>>(h, Vp, nv2, scale);
  k_boxsum<<<64, 256, 0, stream>>>(nv2, p2);
  k_gemm_mfma<<<dim3(4, 128), 256, 0, stream>>>(Vp, ZF + 589824, s);
  k_fcepi<<<4096, 256, 0, stream>>>(s, p2, zn2 + 256, h);
  // ---- bn2 + residual + relu -> s (channel-last), then transpose
  k_bnred1<<<128, 256, 0, stream>>>(h, num, den);
  k_bnmid<<<1, 256, 0, stream>>>(num, den, b2, mu, scal);
  k_bnred2<<<128, 256, 0, stream>>>(h, mu, scal, var);
  k_bntrans<2><<<4096, 256, 0, stream>>>(h, mu, scal, b2, w2, var, xl, s);
  k_outT<<<512, 256, 0, stream>>>(s, out);
}